// Round 2
// baseline (488.048 us; speedup 1.0000x reference)
//
#include <hip/hip_runtime.h>

// ---------------------------------------------------------------------------
// TransformerBlock on MI355X (gfx950).  B=2, S=2048, D=1024, H=16, hd=64,
// HIDDEN=4096.  All GEMMs in bf16 MFMA (16x16x32) with fp32 accumulation.
// Workspace layout (MiB):
//   [0,2) WqT  [2,4) WkT  [4,6) WvT   (contiguous => one [3072][1024] B^T)
//   [6,8) WoT  [8,16) W1T [16,24) W2T
//   [24,32) q   (later reused as sa_bf16)
//   [32,40) k \
//   [40,48) v  | [32,64) later reused as h (gelu out, 4096x4096 bf16)
//   [48,56) x_bf16 |
//   [56,64) ctx    /
// d_out (fp32, 16MiB) doubles as pre-LN scratch for both LN1 and LN2.
// Total ws use: 64 MiB.
// ---------------------------------------------------------------------------

typedef __bf16 bf16x8 __attribute__((ext_vector_type(8)));
typedef float f32x4 __attribute__((ext_vector_type(4)));

#define DIM_ 1024
#define S_LEN 2048
#define NH 16

__device__ __forceinline__ unsigned short f2bf(float f) {
  unsigned u = __float_as_uint(f);
  u = (u + 0x7FFFu + ((u >> 16) & 1u)) >> 16;   // round-to-nearest-even
  return (unsigned short)u;
}
__device__ __forceinline__ float bf2f(unsigned short h) {
  return __uint_as_float(((unsigned)h) << 16);
}
__device__ __forceinline__ f32x4 mfma16(bf16x8 a, bf16x8 b, f32x4 c) {
  return __builtin_amdgcn_mfma_f32_16x16x32_bf16(a, b, c, 0, 0, 0);
}
__device__ __forceinline__ void gload_lds16(const void* g, void* l) {
  __builtin_amdgcn_global_load_lds(
      (const __attribute__((address_space(1))) void*)g,
      (__attribute__((address_space(3))) void*)l, 16, 0, 0);
}
// XOR swizzle on 8-element k-blocks within a 64-element row (bank spread)
__device__ __forceinline__ int swz(int row) { return ((row ^ (row >> 3)) & 7) << 3; }

// ---------------------------------------------------------------------------
// Transpose + fp32->bf16 convert:  W[K][N] fp32  ->  Wt[N][K] bf16
// ---------------------------------------------------------------------------
__global__ __launch_bounds__(256) void trans_cvt(
    const float* __restrict__ W, unsigned short* __restrict__ Wt, int K, int N)
{
  __shared__ float tile[64][65];
  const int n0 = blockIdx.x * 64, k0 = blockIdx.y * 64;
  const int tid = threadIdx.x;
  const int tr = tid >> 4, tc = (tid & 15) << 2;
#pragma unroll
  for (int rr = 0; rr < 64; rr += 16) {
    const float4 v = *(const float4*)&W[(size_t)(k0 + tr + rr) * N + n0 + tc];
    tile[tr + rr][tc + 0] = v.x; tile[tr + rr][tc + 1] = v.y;
    tile[tr + rr][tc + 2] = v.z; tile[tr + rr][tc + 3] = v.w;
  }
  __syncthreads();
#pragma unroll
  for (int nn = 0; nn < 64; nn += 16) {
    const int n = tr + nn;
    ushort4 o;
    o.x = f2bf(tile[tc + 0][n]);
    o.y = f2bf(tile[tc + 1][n]);
    o.z = f2bf(tile[tc + 2][n]);
    o.w = f2bf(tile[tc + 3][n]);
    *(ushort4*)&Wt[(size_t)(n0 + n) * K + k0 + tc] = o;
  }
}

__global__ void cvt_bf16(const float* __restrict__ in,
                         unsigned short* __restrict__ out, int n4)
{
  const int i = blockIdx.x * blockDim.x + threadIdx.x;
  if (i >= n4) return;
  const float4 v = ((const float4*)in)[i];
  ushort4 o = { f2bf(v.x), f2bf(v.y), f2bf(v.z), f2bf(v.w) };
  ((ushort4*)out)[i] = o;
}

// ---------------------------------------------------------------------------
// GEMM: C[M][N] = A[M][K] * Bt[N][K]^T (+bias) with epilogue variants.
// 128x128 tile, BK=64, 256 threads (2x2 waves of 64x64), 16x16x32 bf16 MFMA.
// EPI 0: fused QKV scatter to (b,h,s,hd) bf16; col>>10 selects q/k/v (q scaled 1/8)
// EPI 1: fp32 out = acc + bias + resf               (pre-LN1)
// EPI 2: bf16 out = gelu(acc + bias)                (FFN hidden)
// EPI 3: fp32 out = acc + bias + bf2f(resb)         (pre-LN2)
// ---------------------------------------------------------------------------
template <int EPI>
__global__ __launch_bounds__(256) void gemm_bt(
    const unsigned short* __restrict__ A,
    const unsigned short* __restrict__ Bt,
    const float* __restrict__ bias,
    const float* __restrict__ bias2,
    const float* __restrict__ bias3,
    int N, int K,
    float* __restrict__ fout,
    unsigned short* __restrict__ bout,
    const float* __restrict__ resf,
    const unsigned short* __restrict__ resb)
{
  __shared__ __align__(16) unsigned short As[128 * 64];
  __shared__ __align__(16) unsigned short Bs[128 * 64];
  const int tn = blockIdx.x, tm = blockIdx.y;
  const int tid = threadIdx.x;
  const int wid = tid >> 6, lane = tid & 63;
  const int wm = wid >> 1, wn = wid & 1;
  const int l15 = lane & 15, lg = lane >> 4;
  const int srow = lane >> 3, sk8 = (lane & 7) << 3;

  f32x4 acc[4][4];
#pragma unroll
  for (int i = 0; i < 4; ++i)
#pragma unroll
    for (int j = 0; j < 4; ++j) acc[i][j] = (f32x4){0.f, 0.f, 0.f, 0.f};

  const size_t abase = (size_t)(tm * 128) * K;
  const size_t bbase = (size_t)(tn * 128) * K;

  for (int kk = 0; kk < K; kk += 64) {
    __syncthreads();
#pragma unroll
    for (int s = 0; s < 4; ++s) {
      const int row = wid * 32 + s * 8 + srow;
      const int sw = sk8 ^ swz(row);
      gload_lds16(A + abase + (size_t)row * K + kk + sw, &As[(wid * 32 + s * 8) * 64]);
      gload_lds16(Bt + bbase + (size_t)row * K + kk + sw, &Bs[(wid * 32 + s * 8) * 64]);
    }
    __syncthreads();
#pragma unroll
    for (int sub = 0; sub < 2; ++sub) {
      bf16x8 af[4], bfr[4];
#pragma unroll
      for (int mr = 0; mr < 4; ++mr) {
        const int row = wm * 64 + mr * 16 + l15;
        af[mr] = *(const bf16x8*)&As[row * 64 + ((sub * 32 + lg * 8) ^ swz(row))];
      }
#pragma unroll
      for (int nr = 0; nr < 4; ++nr) {
        const int row = wn * 64 + nr * 16 + l15;
        bfr[nr] = *(const bf16x8*)&Bs[row * 64 + ((sub * 32 + lg * 8) ^ swz(row))];
      }
#pragma unroll
      for (int mr = 0; mr < 4; ++mr)
#pragma unroll
        for (int nr = 0; nr < 4; ++nr)
          acc[mr][nr] = mfma16(af[mr], bfr[nr], acc[mr][nr]);
    }
  }

  // epilogue; C layout: col = lane&15, row = (lane>>4)*4 + reg
#pragma unroll
  for (int nr = 0; nr < 4; ++nr) {
    const int col = tn * 128 + wn * 64 + nr * 16 + l15;
    float bv;
    int which = 0, c = col;
    if (EPI == 0) {
      which = col >> 10;
      c = col & 1023;
      const float* bp = (which == 0) ? bias : (which == 1) ? bias2 : bias3;
      bv = bp[c];
    } else {
      bv = bias[col];
    }
#pragma unroll
    for (int mr = 0; mr < 4; ++mr) {
#pragma unroll
      for (int j = 0; j < 4; ++j) {
        const int row = tm * 128 + wm * 64 + mr * 16 + lg * 4 + j;
        float v = acc[mr][nr][j] + bv;
        if (EPI == 0) {
          if (which == 0) v *= 0.125f;           // 1/sqrt(hd)
          const int b = row >> 11, s = row & 2047, h = c >> 6, hd = c & 63;
          bout[(size_t)which * 4194304 +
               (((size_t)(b * NH + h)) * S_LEN + s) * 64 + hd] = f2bf(v);
        } else if (EPI == 1) {
          fout[(size_t)row * N + col] = v + resf[(size_t)row * N + col];
        } else if (EPI == 2) {
          const float gl = 0.5f * v * (1.f + erff(v * 0.70710678118654752f));
          bout[(size_t)row * N + col] = f2bf(gl);
        } else {
          fout[(size_t)row * N + col] = v + bf2f(resb[(size_t)row * N + col]);
        }
      }
    }
  }
}

// ---------------------------------------------------------------------------
// Flash attention fwd.  grid (qtile=32, bh=32), 256 threads = 4 waves.
// Wave w owns 16 q rows; loop over 32 kv tiles of 64.
// q,k,v layout: (bh, s, 64) bf16.  ctx out: (token, 1024) bf16.
// ---------------------------------------------------------------------------
__global__ __launch_bounds__(256) void attn_fwd(
    const unsigned short* __restrict__ qg,
    const unsigned short* __restrict__ kg,
    const unsigned short* __restrict__ vg,
    const int* __restrict__ amask,
    unsigned short* __restrict__ ctx)
{
  __shared__ __align__(16) unsigned short Ks[64 * 64];
  __shared__ __align__(16) unsigned short Vs[64 * 64];   // [hd][kv] swizzled
  __shared__ __align__(16) unsigned short Ps[4][16 * 64];
  __shared__ int mk[64];

  const int qt = blockIdx.x, bh = blockIdx.y;
  const int b = bh >> 4, h = bh & 15;
  const int tid = threadIdx.x;
  const int wid = tid >> 6, lane = tid & 63;
  const int l15 = lane & 15, lg = lane >> 4;
  const int srow = lane >> 3, sk8 = (lane & 7) << 3;

  const size_t qoff = (((size_t)bh * S_LEN) + qt * 64 + wid * 16 + l15) * 64 + lg * 8;
  const bf16x8 aq0 = *(const bf16x8*)&qg[qoff];
  const bf16x8 aq1 = *(const bf16x8*)&qg[qoff + 32];

  f32x4 o_[4];
#pragma unroll
  for (int n = 0; n < 4; ++n) o_[n] = (f32x4){0.f, 0.f, 0.f, 0.f};
  float mj[4]  = {-3e38f, -3e38f, -3e38f, -3e38f};
  float lsj[4] = {0.f, 0.f, 0.f, 0.f};

  const size_t kvbase = (size_t)bh * S_LEN * 64;
  unsigned short* Pw = &Ps[wid][0];

  for (int t = 0; t < S_LEN / 64; ++t) {
    __syncthreads();
    // stage K (pre-swizzled global source -> linear LDS)
#pragma unroll
    for (int s5 = 0; s5 < 2; ++s5) {
      const int row = wid * 16 + s5 * 8 + srow;
      gload_lds16(kg + kvbase + (size_t)(t * 64 + row) * 64 + (sk8 ^ swz(row)),
                  &Ks[(wid * 16 + s5 * 8) * 64]);
    }
    // stage V transposed [hd][kv^swz(hd)]
    {
      const int kv = tid >> 3;
      const int c0 = (tid & 7) << 3;
#pragma unroll
      for (int p = 0; p < 2; ++p) {
        const int kvr = kv + p * 32;
        const uint4 raw = *(const uint4*)(vg + kvbase + (size_t)(t * 64 + kvr) * 64 + c0);
        const unsigned short* pr = (const unsigned short*)&raw;
#pragma unroll
        for (int j = 0; j < 8; ++j) {
          const int hd = c0 + j;
          Vs[hd * 64 + (kvr ^ swz(hd))] = pr[j];
        }
      }
    }
    if (tid < 64) mk[tid] = amask[b * S_LEN + t * 64 + tid];
    __syncthreads();

    // QK^T: A=Q(16xq,32xhd), B=K^T -> scores 16x64
    f32x4 sf[4];
#pragma unroll
    for (int nr = 0; nr < 4; ++nr) {
      const int kvloc = nr * 16 + l15;
      const int e = swz(kvloc);
      f32x4 a = (f32x4){0.f, 0.f, 0.f, 0.f};
      const bf16x8 bk0 = *(const bf16x8*)&Ks[kvloc * 64 + ((lg * 8) ^ e)];
      const bf16x8 bk1 = *(const bf16x8*)&Ks[kvloc * 64 + ((32 + lg * 8) ^ e)];
      a = mfma16(aq0, bk0, a);
      a = mfma16(aq1, bk1, a);
      sf[nr] = a;
    }
#pragma unroll
    for (int nr = 0; nr < 4; ++nr)
      if (mk[nr * 16 + l15] == 0)
        sf[nr] = (f32x4){-3e38f, -3e38f, -3e38f, -3e38f};

    // online softmax (rows j; 16-lane groups share rows)
    float pv[4][4];
#pragma unroll
    for (int j = 0; j < 4; ++j) {
      float tmax = fmaxf(fmaxf(sf[0][j], sf[1][j]), fmaxf(sf[2][j], sf[3][j]));
#pragma unroll
      for (int off = 1; off < 16; off <<= 1)
        tmax = fmaxf(tmax, __shfl_xor(tmax, off));
      const float mn = fmaxf(mj[j], tmax);
      const float sc = __expf(mj[j] - mn);
      mj[j] = mn;
      lsj[j] *= sc;
      o_[0][j] *= sc; o_[1][j] *= sc; o_[2][j] *= sc; o_[3][j] *= sc;
#pragma unroll
      for (int nr = 0; nr < 4; ++nr) {
        const float p = __expf(sf[nr][j] - mn);
        pv[nr][j] = p;
        lsj[j] += p;
      }
    }

    // P: C-layout -> per-wave LDS (swizzled) -> A-layout frags
    asm volatile("s_waitcnt lgkmcnt(0)" ::: "memory");
#pragma unroll
    for (int j = 0; j < 4; ++j) {
      const int qr = lg * 4 + j;
      const int e = swz(qr);
#pragma unroll
      for (int nr = 0; nr < 4; ++nr)
        Pw[qr * 64 + ((nr * 16 + l15) ^ e)] = f2bf(pv[nr][j]);
    }
    asm volatile("s_waitcnt lgkmcnt(0)" ::: "memory");
    {
      const int e = swz(l15);
      const bf16x8 pa0 = *(const bf16x8*)&Pw[l15 * 64 + ((lg * 8) ^ e)];
      const bf16x8 pa1 = *(const bf16x8*)&Pw[l15 * 64 + ((32 + lg * 8) ^ e)];
#pragma unroll
      for (int n = 0; n < 4; ++n) {
        const int hd = n * 16 + l15;
        const int eh = swz(hd);
        const bf16x8 bv0 = *(const bf16x8*)&Vs[hd * 64 + ((lg * 8) ^ eh)];
        const bf16x8 bv1 = *(const bf16x8*)&Vs[hd * 64 + ((32 + lg * 8) ^ eh)];
        o_[n] = mfma16(pa0, bv0, o_[n]);
        o_[n] = mfma16(pa1, bv1, o_[n]);
      }
    }
  }

  float rinv[4];
#pragma unroll
  for (int j = 0; j < 4; ++j) {
    float s = lsj[j];
#pragma unroll
    for (int off = 1; off < 16; off <<= 1) s += __shfl_xor(s, off);
    rinv[j] = 1.f / s;
  }
#pragma unroll
  for (int n = 0; n < 4; ++n) {
#pragma unroll
    for (int j = 0; j < 4; ++j) {
      const int sr = qt * 64 + wid * 16 + lg * 4 + j;
      const size_t idx = ((size_t)b * S_LEN + sr) * DIM_ + h * 64 + n * 16 + l15;
      ctx[idx] = f2bf(o_[n][j] * rinv[j]);
    }
  }
}

// ---------------------------------------------------------------------------
// LayerNorm over rows of 1024 fp32.  OUTBF=1 -> bf16 out, else fp32 out.
// Safe in-place for fp32 (row-local: all reads precede writes per block).
// ---------------------------------------------------------------------------
template <int OUTBF>
__global__ __launch_bounds__(256) void ln_fused(
    const float* __restrict__ in, const float* __restrict__ g,
    const float* __restrict__ be,
    float* __restrict__ fout, unsigned short* __restrict__ bout)
{
  const int row = blockIdx.x, tid = threadIdx.x;
  const float4 v = ((const float4*)(in + (size_t)row * DIM_))[tid];
  float s = v.x + v.y + v.z + v.w;
  float s2 = v.x * v.x + v.y * v.y + v.z * v.z + v.w * v.w;
#pragma unroll
  for (int off = 1; off < 64; off <<= 1) {
    s += __shfl_xor(s, off);
    s2 += __shfl_xor(s2, off);
  }
  __shared__ float rs[4], rs2[4];
  if ((tid & 63) == 0) { rs[tid >> 6] = s; rs2[tid >> 6] = s2; }
  __syncthreads();
  s  = rs[0] + rs[1] + rs[2] + rs[3];
  s2 = rs2[0] + rs2[1] + rs2[2] + rs2[3];
  const float mean = s * (1.f / DIM_);
  const float var = fmaxf(s2 * (1.f / DIM_) - mean * mean, 0.f);
  const float inv = rsqrtf(var + 1e-12f);
  const float4 gv = ((const float4*)g)[tid];
  const float4 bv = ((const float4*)be)[tid];
  const float o0 = (v.x - mean) * inv * gv.x + bv.x;
  const float o1 = (v.y - mean) * inv * gv.y + bv.y;
  const float o2 = (v.z - mean) * inv * gv.z + bv.z;
  const float o3 = (v.w - mean) * inv * gv.w + bv.w;
  if (OUTBF) {
    ushort4 o = { f2bf(o0), f2bf(o1), f2bf(o2), f2bf(o3) };
    ((ushort4*)(bout + (size_t)row * DIM_))[tid] = o;
  } else {
    ((float4*)(fout + (size_t)row * DIM_))[tid] = make_float4(o0, o1, o2, o3);
  }
}

// ---------------------------------------------------------------------------
extern "C" void kernel_launch(void* const* d_in, const int* in_sizes, int n_in,
                              void* d_out, int out_size, void* d_ws, size_t ws_size,
                              hipStream_t stream)
{
  const float* x   = (const float*)d_in[0];
  const int* amask = (const int*)d_in[1];
  const float* Wq  = (const float*)d_in[2];
  const float* bq  = (const float*)d_in[3];
  const float* Wk  = (const float*)d_in[4];
  const float* bk  = (const float*)d_in[5];
  const float* Wv  = (const float*)d_in[6];
  const float* bv  = (const float*)d_in[7];
  const float* Wo  = (const float*)d_in[8];
  const float* bo  = (const float*)d_in[9];
  const float* g1  = (const float*)d_in[10];
  const float* be1 = (const float*)d_in[11];
  const float* W1  = (const float*)d_in[12];
  const float* b1  = (const float*)d_in[13];
  const float* W2  = (const float*)d_in[14];
  const float* b2  = (const float*)d_in[15];
  const float* g2  = (const float*)d_in[16];
  const float* be2 = (const float*)d_in[17];
  float* out = (float*)d_out;

  char* ws = (char*)d_ws;
  const size_t MB = (size_t)1 << 20;
  unsigned short* wqkvT = (unsigned short*)(ws + 0 * MB);   // [3072][1024]
  unsigned short* wqt = wqkvT;
  unsigned short* wkt = (unsigned short*)(ws + 2 * MB);
  unsigned short* wvt = (unsigned short*)(ws + 4 * MB);
  unsigned short* wot = (unsigned short*)(ws + 6 * MB);
  unsigned short* w1t = (unsigned short*)(ws + 8 * MB);
  unsigned short* w2t = (unsigned short*)(ws + 16 * MB);
  unsigned short* qb  = (unsigned short*)(ws + 24 * MB);    // q,k,v contiguous
  unsigned short* xb  = (unsigned short*)(ws + 48 * MB);
  unsigned short* ctx = (unsigned short*)(ws + 56 * MB);
  unsigned short* sab = qb;                                  // reuse after attn
  unsigned short* hb  = (unsigned short*)(ws + 32 * MB);     // reuse [32,64)
  float* preln = out;                                        // d_out as scratch

  // weight transposes + input convert
  trans_cvt<<<dim3(16, 16), 256, 0, stream>>>(Wq, wqt, 1024, 1024);
  trans_cvt<<<dim3(16, 16), 256, 0, stream>>>(Wk, wkt, 1024, 1024);
  trans_cvt<<<dim3(16, 16), 256, 0, stream>>>(Wv, wvt, 1024, 1024);
  trans_cvt<<<dim3(16, 16), 256, 0, stream>>>(Wo, wot, 1024, 1024);
  trans_cvt<<<dim3(64, 16), 256, 0, stream>>>(W1, w1t, 1024, 4096);
  trans_cvt<<<dim3(16, 64), 256, 0, stream>>>(W2, w2t, 4096, 1024);
  cvt_bf16<<<4096, 256, 0, stream>>>(x, xb, 4096 * 1024 / 4);

  // fused QKV projection (N=3072)
  gemm_bt<0><<<dim3(24, 32), 256, 0, stream>>>(xb, wqkvT, bq, bk, bv,
      3072, 1024, nullptr, qb, nullptr, nullptr);

  // attention
  attn_fwd<<<dim3(32, 32), 256, 0, stream>>>(qb, qb + 4194304, qb + 2 * 4194304,
                                             amask, ctx);

  // O-proj + residual(x) -> preln (d_out)
  gemm_bt<1><<<dim3(8, 32), 256, 0, stream>>>(ctx, wot, bo, nullptr, nullptr,
      1024, 1024, preln, nullptr, x, nullptr);
  ln_fused<1><<<4096, 256, 0, stream>>>(preln, g1, be1, nullptr, sab);

  // FFN
  gemm_bt<2><<<dim3(32, 32), 256, 0, stream>>>(sab, w1t, b1, nullptr, nullptr,
      4096, 1024, nullptr, hb, nullptr, nullptr);
  gemm_bt<3><<<dim3(8, 32), 256, 0, stream>>>(hb, w2t, b2, nullptr, nullptr,
      1024, 4096, preln, nullptr, nullptr, sab);
  ln_fused<0><<<4096, 256, 0, stream>>>(preln, g2, be2, out, nullptr);
}

// Round 4
// 406.396 us; speedup vs baseline: 1.2009x; 1.2009x over previous
//
#include <hip/hip_runtime.h>

// ---------------------------------------------------------------------------
// TransformerBlock on MI355X (gfx950).  B=2, S=2048, D=1024, H=16, hd=64,
// HIDDEN=4096.  bf16 MFMA (16x16x32), fp32 accum/softmax/LN.
// Workspace (MiB): [0,6) WqkvT  [6,8) WoT  [8,16) W1T  [16,24) W2T
//   [24,32) q (later sab)  [32,40) k  [40,48) v  [48,56) xb (later vt)
//   [56,64) ctx ; [32,64) later reused as h (FFN hidden bf16)
// d_out doubles as fp32 pre-LN scratch. Total 64 MiB.
// ---------------------------------------------------------------------------

typedef __bf16 bf16x8 __attribute__((ext_vector_type(8)));
typedef float f32x4 __attribute__((ext_vector_type(4)));

#define DIM_ 1024
#define S_LEN 2048
#define NH 16

__device__ __forceinline__ unsigned short f2bf(float f) {
  unsigned u = __float_as_uint(f);
  u = (u + 0x7FFFu + ((u >> 16) & 1u)) >> 16;   // RNE
  return (unsigned short)u;
}
__device__ __forceinline__ float bf2f(unsigned short h) {
  return __uint_as_float(((unsigned)h) << 16);
}
__device__ __forceinline__ f32x4 mfma16(bf16x8 a, bf16x8 b, f32x4 c) {
  return __builtin_amdgcn_mfma_f32_16x16x32_bf16(a, b, c, 0, 0, 0);
}
__device__ __forceinline__ void gload_lds16(const void* g, void* l) {
  __builtin_amdgcn_global_load_lds(
      (const __attribute__((address_space(1))) void*)g,
      (__attribute__((address_space(3))) void*)l, 16, 0, 0);
}
__device__ __forceinline__ int swz(int row) { return ((row ^ (row >> 3)) & 7) << 3; }

// ---------------------------------------------------------------------------
// W[K][N] fp32 -> Wt[N][K] bf16
// ---------------------------------------------------------------------------
__global__ __launch_bounds__(256) void trans_cvt(
    const float* __restrict__ W, unsigned short* __restrict__ Wt, int K, int N)
{
  __shared__ float tile[64][65];
  const int n0 = blockIdx.x * 64, k0 = blockIdx.y * 64;
  const int tid = threadIdx.x;
  const int tr = tid >> 4, tc = (tid & 15) << 2;
#pragma unroll
  for (int rr = 0; rr < 64; rr += 16) {
    const float4 v = *(const float4*)&W[(size_t)(k0 + tr + rr) * N + n0 + tc];
    tile[tr + rr][tc + 0] = v.x; tile[tr + rr][tc + 1] = v.y;
    tile[tr + rr][tc + 2] = v.z; tile[tr + rr][tc + 3] = v.w;
  }
  __syncthreads();
#pragma unroll
  for (int nn = 0; nn < 64; nn += 16) {
    const int n = tr + nn;
    ushort4 o;
    o.x = f2bf(tile[tc + 0][n]);
    o.y = f2bf(tile[tc + 1][n]);
    o.z = f2bf(tile[tc + 2][n]);
    o.w = f2bf(tile[tc + 3][n]);
    *(ushort4*)&Wt[(size_t)(n0 + n) * K + k0 + tc] = o;
  }
}

__global__ void cvt_bf16(const float* __restrict__ in,
                         unsigned short* __restrict__ out, int n4)
{
  const int i = blockIdx.x * blockDim.x + threadIdx.x;
  if (i >= n4) return;
  const float4 v = ((const float4*)in)[i];
  ushort4 o = { f2bf(v.x), f2bf(v.y), f2bf(v.z), f2bf(v.w) };
  ((ushort4*)out)[i] = o;
}

// ---------------------------------------------------------------------------
// V (bh,s,64) bf16 -> Vt (bh,64,s) bf16
// ---------------------------------------------------------------------------
__global__ __launch_bounds__(256) void trans_v(
    const unsigned short* __restrict__ v, unsigned short* __restrict__ vt)
{
  __shared__ unsigned short tile[64][66];
  const int st = blockIdx.x, bh = blockIdx.y;
  const int tid = threadIdx.x;
  const int r = tid >> 3, c = (tid & 7) << 3;
  const size_t base = (size_t)bh * (S_LEN * 64);
#pragma unroll
  for (int p = 0; p < 2; ++p) {
    const int s = r + p * 32;
    const uint4 raw = *(const uint4*)(v + base + (size_t)(st * 64 + s) * 64 + c);
    const unsigned short* pr = (const unsigned short*)&raw;
#pragma unroll
    for (int j = 0; j < 8; ++j) tile[s][c + j] = pr[j];
  }
  __syncthreads();
#pragma unroll
  for (int p = 0; p < 2; ++p) {
    const int hd = r + p * 32;
    ushort4 o[2];
#pragma unroll
    for (int j = 0; j < 8; ++j) ((unsigned short*)o)[j] = tile[c + j][hd];
    *(uint4*)(vt + (size_t)bh * (64 * S_LEN) + (size_t)hd * S_LEN + st * 64 + c) =
        *(const uint4*)o;
  }
}

// ---------------------------------------------------------------------------
// GEMM 128x128, BK=64, single-buffer (m97 style).  EPI 0: QKV scatter;
// EPI 2: bf16 gelu(acc+bias).
// ---------------------------------------------------------------------------
template <int EPI>
__global__ __launch_bounds__(256) void gemm_bt(
    const unsigned short* __restrict__ A,
    const unsigned short* __restrict__ Bt,
    const float* __restrict__ bias,
    const float* __restrict__ bias2,
    const float* __restrict__ bias3,
    int N, int K,
    unsigned short* __restrict__ bout)
{
  __shared__ __align__(16) unsigned short As[128 * 64];
  __shared__ __align__(16) unsigned short Bs[128 * 64];
  const int tn = blockIdx.x, tm = blockIdx.y;
  const int tid = threadIdx.x;
  const int wid = tid >> 6, lane = tid & 63;
  const int wm = wid >> 1, wn = wid & 1;
  const int l15 = lane & 15, lg = lane >> 4;
  const int srow = lane >> 3, sk8 = (lane & 7) << 3;

  f32x4 acc[4][4];
#pragma unroll
  for (int i = 0; i < 4; ++i)
#pragma unroll
    for (int j = 0; j < 4; ++j) acc[i][j] = (f32x4){0.f, 0.f, 0.f, 0.f};

  const size_t abase = (size_t)(tm * 128) * K;
  const size_t bbase = (size_t)(tn * 128) * K;

  for (int kk = 0; kk < K; kk += 64) {
    __syncthreads();
#pragma unroll
    for (int s = 0; s < 4; ++s) {
      const int row = wid * 32 + s * 8 + srow;
      const int sw = sk8 ^ swz(row);
      gload_lds16(A + abase + (size_t)row * K + kk + sw, &As[(wid * 32 + s * 8) * 64]);
      gload_lds16(Bt + bbase + (size_t)row * K + kk + sw, &Bs[(wid * 32 + s * 8) * 64]);
    }
    __syncthreads();
#pragma unroll
    for (int sub = 0; sub < 2; ++sub) {
      bf16x8 af[4], bfr[4];
#pragma unroll
      for (int mr = 0; mr < 4; ++mr) {
        const int row = wm * 64 + mr * 16 + l15;
        af[mr] = *(const bf16x8*)&As[row * 64 + ((sub * 32 + lg * 8) ^ swz(row))];
      }
#pragma unroll
      for (int nr = 0; nr < 4; ++nr) {
        const int row = wn * 64 + nr * 16 + l15;
        bfr[nr] = *(const bf16x8*)&Bs[row * 64 + ((sub * 32 + lg * 8) ^ swz(row))];
      }
#pragma unroll
      for (int mr = 0; mr < 4; ++mr)
#pragma unroll
        for (int nr = 0; nr < 4; ++nr)
          acc[mr][nr] = mfma16(af[mr], bfr[nr], acc[mr][nr]);
    }
  }

#pragma unroll
  for (int nr = 0; nr < 4; ++nr) {
    const int col = tn * 128 + wn * 64 + nr * 16 + l15;
    float bv;
    int which = 0, c = col;
    if (EPI == 0) {
      which = col >> 10;
      c = col & 1023;
      const float* bp = (which == 0) ? bias : (which == 1) ? bias2 : bias3;
      bv = bp[c];
    } else {
      bv = bias[col];
    }
#pragma unroll
    for (int mr = 0; mr < 4; ++mr) {
#pragma unroll
      for (int j = 0; j < 4; ++j) {
        const int row = tm * 128 + wm * 64 + mr * 16 + lg * 4 + j;
        float v = acc[mr][nr][j] + bv;
        if (EPI == 0) {
          if (which == 0) v *= 0.125f;           // 1/sqrt(hd)
          const int b = row >> 11, s = row & 2047, h = c >> 6, hd = c & 63;
          bout[(size_t)which * 4194304 +
               (((size_t)(b * NH + h)) * S_LEN + s) * 64 + hd] = f2bf(v);
        } else {
          const float gl = 0.5f * v * (1.f + erff(v * 0.70710678118654752f));
          bout[(size_t)row * N + col] = f2bf(gl);
        }
      }
    }
  }
}

// ---------------------------------------------------------------------------
// GEMM 64x128, BK=64, DOUBLE-buffered (for N=1024 GEMMs: grid 512 = 2/CU).
// EPI 1: fp32 out = acc + bias + resf    (O-proj + residual x)
// EPI 3: fp32 out = acc + bias + bf2f(resb)  (FFN2 + residual sa)
// ---------------------------------------------------------------------------
template <int EPI>
__global__ __launch_bounds__(256) void gemm64(
    const unsigned short* __restrict__ A,
    const unsigned short* __restrict__ Bt,
    const float* __restrict__ bias,
    int N, int K,
    float* __restrict__ fout,
    const float* __restrict__ resf,
    const unsigned short* __restrict__ resb)
{
  __shared__ __align__(16) unsigned short As[2][64 * 64];
  __shared__ __align__(16) unsigned short Bs[2][128 * 64];
  const int tn = blockIdx.x, tm = blockIdx.y;
  const int tid = threadIdx.x;
  const int wid = tid >> 6, lane = tid & 63;
  const int wm = wid >> 1, wn = wid & 1;
  const int l15 = lane & 15, lg = lane >> 4;
  const int srow = lane >> 3, sk8 = (lane & 7) << 3;

  f32x4 acc[2][4];
#pragma unroll
  for (int i = 0; i < 2; ++i)
#pragma unroll
    for (int j = 0; j < 4; ++j) acc[i][j] = (f32x4){0.f, 0.f, 0.f, 0.f};

  const size_t abase = (size_t)(tm * 64) * K;
  const size_t bbase = (size_t)(tn * 128) * K;

  auto STAGE = [&](int bufn, int kk) {
#pragma unroll
    for (int s = 0; s < 2; ++s) {
      const int row = wid * 16 + s * 8 + srow;
      gload_lds16(A + abase + (size_t)row * K + kk + (sk8 ^ swz(row)),
                  &As[bufn][(wid * 16 + s * 8) * 64]);
    }
#pragma unroll
    for (int s = 0; s < 4; ++s) {
      const int row = wid * 32 + s * 8 + srow;
      gload_lds16(Bt + bbase + (size_t)row * K + kk + (sk8 ^ swz(row)),
                  &Bs[bufn][(wid * 32 + s * 8) * 64]);
    }
  };

  STAGE(0, 0);
  __syncthreads();
  int cur = 0;
  for (int kk = 0; kk < K; kk += 64) {
    if (kk + 64 < K) STAGE(cur ^ 1, kk + 64);
#pragma unroll
    for (int sub = 0; sub < 2; ++sub) {
      bf16x8 af[2], bfr[4];
#pragma unroll
      for (int mr = 0; mr < 2; ++mr) {
        const int row = wm * 32 + mr * 16 + l15;
        af[mr] = *(const bf16x8*)&As[cur][row * 64 + ((sub * 32 + lg * 8) ^ swz(row))];
      }
#pragma unroll
      for (int nr = 0; nr < 4; ++nr) {
        const int row = wn * 64 + nr * 16 + l15;
        bfr[nr] = *(const bf16x8*)&Bs[cur][row * 64 + ((sub * 32 + lg * 8) ^ swz(row))];
      }
#pragma unroll
      for (int mr = 0; mr < 2; ++mr)
#pragma unroll
        for (int nr = 0; nr < 4; ++nr)
          acc[mr][nr] = mfma16(af[mr], bfr[nr], acc[mr][nr]);
    }
    __syncthreads();
    cur ^= 1;
  }

#pragma unroll
  for (int nr = 0; nr < 4; ++nr) {
    const int col = tn * 128 + wn * 64 + nr * 16 + l15;
    const float bv = bias[col];
#pragma unroll
    for (int mr = 0; mr < 2; ++mr) {
#pragma unroll
      for (int j = 0; j < 4; ++j) {
        const int row = tm * 64 + wm * 32 + mr * 16 + lg * 4 + j;
        const float v = acc[mr][nr][j] + bv;
        if (EPI == 1) {
          fout[(size_t)row * N + col] = v + resf[(size_t)row * N + col];
        } else {
          fout[(size_t)row * N + col] = v + bf2f(resb[(size_t)row * N + col]);
        }
      }
    }
  }
}

// ---------------------------------------------------------------------------
// Flash attention fwd.  1D grid 512 blocks, XCD-grouped: the 16 q-tiles of a
// bh land on one XCD (KV stays L2-resident).  512 threads = 8 waves, each
// wave 16 q-rows (128 q-rows/block).  K/V double-buffered, 1 barrier/tile.
// q,k: (bh,s,64);  vt: (bh,64,s);  ctx out: (token,1024) bf16.
// ---------------------------------------------------------------------------
__global__ __launch_bounds__(512) void attn_fwd(
    const unsigned short* __restrict__ qg,
    const unsigned short* __restrict__ kg,
    const unsigned short* __restrict__ vtg,
    const int* __restrict__ amask,
    unsigned short* __restrict__ ctx)
{
  __shared__ __align__(16) unsigned short Ks[2][64 * 64];
  __shared__ __align__(16) unsigned short Vs[2][64 * 64];   // [hd][kv]
  __shared__ __align__(16) unsigned short Ps[8][16 * 72];
  __shared__ int mk[2][64];

  const int bx = blockIdx.x;
  const int qt = (bx >> 3) & 15;
  const int bh = ((bx & 7) << 2) | (bx >> 7);
  const int b = bh >> 4, h = bh & 15;
  const int tid = threadIdx.x;
  const int wid = tid >> 6, lane = tid & 63;
  const int l15 = lane & 15, lg = lane >> 4;
  const int srow = lane >> 3, sk8 = (lane & 7) << 3;

  const size_t qoff =
      (((size_t)bh * S_LEN) + qt * 128 + wid * 16 + l15) * 64 + lg * 8;
  const bf16x8 aq0 = *(const bf16x8*)&qg[qoff];
  const bf16x8 aq1 = *(const bf16x8*)&qg[qoff + 32];

  f32x4 o_[4];
#pragma unroll
  for (int n = 0; n < 4; ++n) o_[n] = (f32x4){0.f, 0.f, 0.f, 0.f};
  float mj[4]  = {-3e38f, -3e38f, -3e38f, -3e38f};
  float lsj[4] = {0.f, 0.f, 0.f, 0.f};

  const size_t kbase  = (size_t)bh * (S_LEN * 64);
  const size_t vtbase = (size_t)bh * (64 * S_LEN);
  unsigned short* Pw = &Ps[wid][0];
  const int rk = wid * 8 + srow;           // staging row (8 rows/wave)
  const int swr = sk8 ^ swz(rk);

  auto STAGE = [&](int bufn, int t) {
    gload_lds16(kg + kbase + (size_t)(t * 64 + rk) * 64 + swr,
                &Ks[bufn][wid * 8 * 64]);
    gload_lds16(vtg + vtbase + (size_t)rk * S_LEN + t * 64 + swr,
                &Vs[bufn][wid * 8 * 64]);
    if (tid < 64) mk[bufn][tid] = amask[b * S_LEN + t * 64 + tid];
  };

  STAGE(0, 0);
  __syncthreads();
  int cur = 0;

  for (int t = 0; t < S_LEN / 64; ++t) {
    if (t + 1 < S_LEN / 64) STAGE(cur ^ 1, t + 1);

    // QK^T -> scores 16x64 (C: col kv = nr*16+l15, row q = lg*4+j)
    f32x4 sf[4];
#pragma unroll
    for (int nr = 0; nr < 4; ++nr) {
      const int kvloc = nr * 16 + l15;
      const int e = swz(kvloc);
      f32x4 a = (f32x4){0.f, 0.f, 0.f, 0.f};
      const bf16x8 bk0 = *(const bf16x8*)&Ks[cur][kvloc * 64 + ((lg * 8) ^ e)];
      const bf16x8 bk1 = *(const bf16x8*)&Ks[cur][kvloc * 64 + ((32 + lg * 8) ^ e)];
      a = mfma16(aq0, bk0, a);
      a = mfma16(aq1, bk1, a);
      sf[nr] = a;
    }
#pragma unroll
    for (int nr = 0; nr < 4; ++nr)
      if (mk[cur][nr * 16 + l15] == 0)
        sf[nr] = (f32x4){-3e38f, -3e38f, -3e38f, -3e38f};

    // online softmax (16-lane groups share q-rows)
    float pv[4][4];
#pragma unroll
    for (int j = 0; j < 4; ++j) {
      float tmax = fmaxf(fmaxf(sf[0][j], sf[1][j]), fmaxf(sf[2][j], sf[3][j]));
#pragma unroll
      for (int off = 1; off < 16; off <<= 1)
        tmax = fmaxf(tmax, __shfl_xor(tmax, off));
      const float mn = fmaxf(mj[j], tmax);
      const float sc = __expf(mj[j] - mn);
      mj[j] = mn;
      lsj[j] *= sc;
      o_[0][j] *= sc; o_[1][j] *= sc; o_[2][j] *= sc; o_[3][j] *= sc;
#pragma unroll
      for (int nr = 0; nr < 4; ++nr) {
        const float p = __expf(sf[nr][j] - mn);
        pv[nr][j] = p;
        lsj[j] += p;
      }
    }

    // P (C-layout) -> per-wave LDS [16][72] -> A-layout frags
    asm volatile("s_waitcnt lgkmcnt(0)" ::: "memory");
#pragma unroll
    for (int j = 0; j < 4; ++j) {
      const int qr = lg * 4 + j;
#pragma unroll
      for (int nr = 0; nr < 4; ++nr)
        Pw[qr * 72 + nr * 16 + l15] = f2bf(pv[nr][j]);
    }
    asm volatile("s_waitcnt lgkmcnt(0)" ::: "memory");
    {
      const bf16x8 pa0 = *(const bf16x8*)&Pw[l15 * 72 + lg * 8];
      const bf16x8 pa1 = *(const bf16x8*)&Pw[l15 * 72 + 32 + lg * 8];
#pragma unroll
      for (int n = 0; n < 4; ++n) {
        const int hd = n * 16 + l15;
        const int eh = swz(hd);
        const bf16x8 bv0 = *(const bf16x8*)&Vs[cur][hd * 64 + ((lg * 8) ^ eh)];
        const bf16x8 bv1 = *(const bf16x8*)&Vs[cur][hd * 64 + ((32 + lg * 8) ^ eh)];
        o_[n] = mfma16(pa0, bv0, o_[n]);
        o_[n] = mfma16(pa1, bv1, o_[n]);
      }
    }
    __syncthreads();
    cur ^= 1;
  }

  float rinv[4];
#pragma unroll
  for (int j = 0; j < 4; ++j) {
    float s = lsj[j];
#pragma unroll
    for (int off = 1; off < 16; off <<= 1) s += __shfl_xor(s, off);
    rinv[j] = 1.f / s;
  }
#pragma unroll
  for (int n = 0; n < 4; ++n) {
#pragma unroll
    for (int j = 0; j < 4; ++j) {
      const int sr = qt * 128 + wid * 16 + lg * 4 + j;
      const size_t idx = ((size_t)b * S_LEN + sr) * DIM_ + h * 64 + n * 16 + l15;
      ctx[idx] = f2bf(o_[n][j] * rinv[j]);
    }
  }
}

// ---------------------------------------------------------------------------
// LayerNorm rows of 1024 fp32.  OUTBF=1 -> bf16 out, else fp32 (in-place ok).
// ---------------------------------------------------------------------------
template <int OUTBF>
__global__ __launch_bounds__(256) void ln_fused(
    const float* __restrict__ in, const float* __restrict__ g,
    const float* __restrict__ be,
    float* __restrict__ fout, unsigned short* __restrict__ bout)
{
  const int row = blockIdx.x, tid = threadIdx.x;
  const float4 v = ((const float4*)(in + (size_t)row * DIM_))[tid];
  float s = v.x + v.y + v.z + v.w;
  float s2 = v.x * v.x + v.y * v.y + v.z * v.z + v.w * v.w;
#pragma unroll
  for (int off = 1; off < 64; off <<= 1) {
    s += __shfl_xor(s, off);
    s2 += __shfl_xor(s2, off);
  }
  __shared__ float rs[4], rs2[4];
  if ((tid & 63) == 0) { rs[tid >> 6] = s; rs2[tid >> 6] = s2; }
  __syncthreads();
  s  = rs[0] + rs[1] + rs[2] + rs[3];
  s2 = rs2[0] + rs2[1] + rs2[2] + rs2[3];
  const float mean = s * (1.f / DIM_);
  const float var = fmaxf(s2 * (1.f / DIM_) - mean * mean, 0.f);
  const float inv = rsqrtf(var + 1e-12f);
  const float4 gv = ((const float4*)g)[tid];
  const float4 bv = ((const float4*)be)[tid];
  const float o0 = (v.x - mean) * inv * gv.x + bv.x;
  const float o1 = (v.y - mean) * inv * gv.y + bv.y;
  const float o2 = (v.z - mean) * inv * gv.z + bv.z;
  const float o3 = (v.w - mean) * inv * gv.w + bv.w;
  if (OUTBF) {
    ushort4 o = { f2bf(o0), f2bf(o1), f2bf(o2), f2bf(o3) };
    ((ushort4*)(bout + (size_t)row * DIM_))[tid] = o;
  } else {
    ((float4*)(fout + (size_t)row * DIM_))[tid] = make_float4(o0, o1, o2, o3);
  }
}

// ---------------------------------------------------------------------------
extern "C" void kernel_launch(void* const* d_in, const int* in_sizes, int n_in,
                              void* d_out, int out_size, void* d_ws, size_t ws_size,
                              hipStream_t stream)
{
  const float* x   = (const float*)d_in[0];
  const int* amask = (const int*)d_in[1];
  const float* Wq  = (const float*)d_in[2];
  const float* bq  = (const float*)d_in[3];
  const float* Wk  = (const float*)d_in[4];
  const float* bk  = (const float*)d_in[5];
  const float* Wv  = (const float*)d_in[6];
  const float* bv  = (const float*)d_in[7];
  const float* Wo  = (const float*)d_in[8];
  const float* bo  = (const float*)d_in[9];
  const float* g1  = (const float*)d_in[10];
  const float* be1 = (const float*)d_in[11];
  const float* W1  = (const float*)d_in[12];
  const float* b1  = (const float*)d_in[13];
  const float* W2  = (const float*)d_in[14];
  const float* b2  = (const float*)d_in[15];
  const float* g2  = (const float*)d_in[16];
  const float* be2 = (const float*)d_in[17];
  float* out = (float*)d_out;

  char* ws = (char*)d_ws;
  const size_t MB = (size_t)1 << 20;
  unsigned short* wqkvT = (unsigned short*)(ws + 0 * MB);   // [3072][1024]
  unsigned short* wqt = wqkvT;
  unsigned short* wkt = (unsigned short*)(ws + 2 * MB);
  unsigned short* wvt = (unsigned short*)(ws + 4 * MB);
  unsigned short* wot = (unsigned short*)(ws + 6 * MB);
  unsigned short* w1t = (unsigned short*)(ws + 8 * MB);
  unsigned short* w2t = (unsigned short*)(ws + 16 * MB);
  unsigned short* qb  = (unsigned short*)(ws + 24 * MB);    // q,k,v contiguous
  unsigned short* xb  = (unsigned short*)(ws + 48 * MB);
  unsigned short* vtb = (unsigned short*)(ws + 48 * MB);    // vt (after xb dead)
  unsigned short* ctx = (unsigned short*)(ws + 56 * MB);
  unsigned short* sab = qb;                                  // reuse after attn
  unsigned short* hb  = (unsigned short*)(ws + 32 * MB);     // reuse [32,64)
  float* preln = out;                                        // d_out as scratch

  trans_cvt<<<dim3(16, 16), 256, 0, stream>>>(Wq, wqt, 1024, 1024);
  trans_cvt<<<dim3(16, 16), 256, 0, stream>>>(Wk, wkt, 1024, 1024);
  trans_cvt<<<dim3(16, 16), 256, 0, stream>>>(Wv, wvt, 1024, 1024);
  trans_cvt<<<dim3(16, 16), 256, 0, stream>>>(Wo, wot, 1024, 1024);
  trans_cvt<<<dim3(64, 16), 256, 0, stream>>>(W1, w1t, 1024, 4096);
  trans_cvt<<<dim3(16, 64), 256, 0, stream>>>(W2, w2t, 4096, 1024);
  cvt_bf16<<<4096, 256, 0, stream>>>(x, xb, 4096 * 1024 / 4);

  // fused QKV projection (N=3072), scatter to (bh,s,hd)
  gemm_bt<0><<<dim3(24, 32), 256, 0, stream>>>(xb, wqkvT, bq, bk, bv,
      3072, 1024, qb);

  // V -> Vt (bh,64,s); xb is dead now
  trans_v<<<dim3(32, 32), 256, 0, stream>>>(qb + 2 * 4194304, vtb);

  // attention (XCD-grouped 1D grid)
  attn_fwd<<<512, 512, 0, stream>>>(qb, qb + 4194304, vtb, amask, ctx);

  // O-proj + bias + residual(x) -> preln (d_out)
  gemm64<1><<<dim3(8, 64), 256, 0, stream>>>(ctx, wot, bo, 1024, 1024,
      preln, x, nullptr);
  ln_fused<1><<<4096, 256, 0, stream>>>(preln, g1, be1, nullptr, sab);

  // FFN
  gemm_bt<2><<<dim3(32, 32), 256, 0, stream>>>(sab, w1t, b1, nullptr, nullptr,
      4096, 1024, hb);
  gemm64<3><<<dim3(8, 64), 256, 0, stream>>>(hb, w2t, b2, 1024, 4096,
      preln, nullptr, sab);
  ln_fused<0><<<4096, 256, 0, stream>>>(preln, g2, be2, out, nullptr);
}

// Round 6
// 395.433 us; speedup vs baseline: 1.2342x; 1.0277x over previous
//
#include <hip/hip_runtime.h>

// ---------------------------------------------------------------------------
// TransformerBlock on MI355X (gfx950).  B=2, S=2048, D=1024, H=16, hd=64,
// HIDDEN=4096.  bf16 MFMA (16x16x32), fp32 accum/softmax/LN.
// Workspace (MiB): [0,6) WqkvT  [6,8) WoT  [8,16) W1T  [16,24) W2T
//   [24,32) q (later sab)  [32,40) k  [40,48) v  [48,56) xb (later vt)
//   [56,64) ctx ; [32,64) later reused as h (FFN hidden bf16)
// d_out doubles as fp32 pre-LN scratch. Total 64 MiB.
// ---------------------------------------------------------------------------

typedef __bf16 bf16x8 __attribute__((ext_vector_type(8)));
typedef __bf16 bf16x4v __attribute__((ext_vector_type(4)));
typedef float f32x4 __attribute__((ext_vector_type(4)));

#define DIM_ 1024
#define S_LEN 2048
#define NH 16

__device__ __forceinline__ unsigned short f2bf(float f) {
  unsigned u = __float_as_uint(f);
  u = (u + 0x7FFFu + ((u >> 16) & 1u)) >> 16;   // RNE
  return (unsigned short)u;
}
__device__ __forceinline__ float bf2f(unsigned short h) {
  return __uint_as_float(((unsigned)h) << 16);
}
__device__ __forceinline__ f32x4 mfma16(bf16x8 a, bf16x8 b, f32x4 c) {
  return __builtin_amdgcn_mfma_f32_16x16x32_bf16(a, b, c, 0, 0, 0);
}
__device__ __forceinline__ void gload_lds16(const void* g, void* l) {
  __builtin_amdgcn_global_load_lds(
      (const __attribute__((address_space(1))) void*)g,
      (__attribute__((address_space(3))) void*)l, 16, 0, 0);
}
__device__ __forceinline__ int swz(int row) { return ((row ^ (row >> 3)) & 7) << 3; }

// ---------------------------------------------------------------------------
// W[K][N] fp32 -> Wt[N][K] bf16
// ---------------------------------------------------------------------------
__global__ __launch_bounds__(256) void trans_cvt(
    const float* __restrict__ W, unsigned short* __restrict__ Wt, int K, int N)
{
  __shared__ float tile[64][65];
  const int n0 = blockIdx.x * 64, k0 = blockIdx.y * 64;
  const int tid = threadIdx.x;
  const int tr = tid >> 4, tc = (tid & 15) << 2;
#pragma unroll
  for (int rr = 0; rr < 64; rr += 16) {
    const float4 v = *(const float4*)&W[(size_t)(k0 + tr + rr) * N + n0 + tc];
    tile[tr + rr][tc + 0] = v.x; tile[tr + rr][tc + 1] = v.y;
    tile[tr + rr][tc + 2] = v.z; tile[tr + rr][tc + 3] = v.w;
  }
  __syncthreads();
#pragma unroll
  for (int nn = 0; nn < 64; nn += 16) {
    const int n = tr + nn;
    ushort4 o;
    o.x = f2bf(tile[tc + 0][n]);
    o.y = f2bf(tile[tc + 1][n]);
    o.z = f2bf(tile[tc + 2][n]);
    o.w = f2bf(tile[tc + 3][n]);
    *(ushort4*)&Wt[(size_t)(n0 + n) * K + k0 + tc] = o;
  }
}

__global__ void cvt_bf16(const float* __restrict__ in,
                         unsigned short* __restrict__ out, int n4)
{
  const int i = blockIdx.x * blockDim.x + threadIdx.x;
  if (i >= n4) return;
  const float4 v = ((const float4*)in)[i];
  ushort4 o = { f2bf(v.x), f2bf(v.y), f2bf(v.z), f2bf(v.w) };
  ((ushort4*)out)[i] = o;
}

// ---------------------------------------------------------------------------
// V (bh,s,64) bf16 -> Vt (bh,64,s) bf16
// ---------------------------------------------------------------------------
__global__ __launch_bounds__(256) void trans_v(
    const unsigned short* __restrict__ v, unsigned short* __restrict__ vt)
{
  __shared__ unsigned short tile[64][66];
  const int st = blockIdx.x, bh = blockIdx.y;
  const int tid = threadIdx.x;
  const int r = tid >> 3, c = (tid & 7) << 3;
  const size_t base = (size_t)bh * (S_LEN * 64);
#pragma unroll
  for (int p = 0; p < 2; ++p) {
    const int s = r + p * 32;
    const uint4 raw = *(const uint4*)(v + base + (size_t)(st * 64 + s) * 64 + c);
    const unsigned short* pr = (const unsigned short*)&raw;
#pragma unroll
    for (int j = 0; j < 8; ++j) tile[s][c + j] = pr[j];
  }
  __syncthreads();
#pragma unroll
  for (int p = 0; p < 2; ++p) {
    const int hd = r + p * 32;
    ushort4 o[2];
#pragma unroll
    for (int j = 0; j < 8; ++j) ((unsigned short*)o)[j] = tile[c + j][hd];
    *(uint4*)(vt + (size_t)bh * (64 * S_LEN) + (size_t)hd * S_LEN + st * 64 + c) =
        *(const uint4*)o;
  }
}

// ---------------------------------------------------------------------------
// GEMM 128x128, BK=64, single-buffer (m97 style).  EPI 0: QKV scatter;
// EPI 2: bf16 gelu(acc+bias).
// ---------------------------------------------------------------------------
template <int EPI>
__global__ __launch_bounds__(256) void gemm_bt(
    const unsigned short* __restrict__ A,
    const unsigned short* __restrict__ Bt,
    const float* __restrict__ bias,
    const float* __restrict__ bias2,
    const float* __restrict__ bias3,
    int N, int K,
    unsigned short* __restrict__ bout)
{
  __shared__ __align__(16) unsigned short As[128 * 64];
  __shared__ __align__(16) unsigned short Bs[128 * 64];
  const int tn = blockIdx.x, tm = blockIdx.y;
  const int tid = threadIdx.x;
  const int wid = tid >> 6, lane = tid & 63;
  const int wm = wid >> 1, wn = wid & 1;
  const int l15 = lane & 15, lg = lane >> 4;
  const int srow = lane >> 3, sk8 = (lane & 7) << 3;

  f32x4 acc[4][4];
#pragma unroll
  for (int i = 0; i < 4; ++i)
#pragma unroll
    for (int j = 0; j < 4; ++j) acc[i][j] = (f32x4){0.f, 0.f, 0.f, 0.f};

  const size_t abase = (size_t)(tm * 128) * K;
  const size_t bbase = (size_t)(tn * 128) * K;

  for (int kk = 0; kk < K; kk += 64) {
    __syncthreads();
#pragma unroll
    for (int s = 0; s < 4; ++s) {
      const int row = wid * 32 + s * 8 + srow;
      const int sw = sk8 ^ swz(row);
      gload_lds16(A + abase + (size_t)row * K + kk + sw, &As[(wid * 32 + s * 8) * 64]);
      gload_lds16(Bt + bbase + (size_t)row * K + kk + sw, &Bs[(wid * 32 + s * 8) * 64]);
    }
    __syncthreads();
#pragma unroll
    for (int sub = 0; sub < 2; ++sub) {
      bf16x8 af[4], bfr[4];
#pragma unroll
      for (int mr = 0; mr < 4; ++mr) {
        const int row = wm * 64 + mr * 16 + l15;
        af[mr] = *(const bf16x8*)&As[row * 64 + ((sub * 32 + lg * 8) ^ swz(row))];
      }
#pragma unroll
      for (int nr = 0; nr < 4; ++nr) {
        const int row = wn * 64 + nr * 16 + l15;
        bfr[nr] = *(const bf16x8*)&Bs[row * 64 + ((sub * 32 + lg * 8) ^ swz(row))];
      }
#pragma unroll
      for (int mr = 0; mr < 4; ++mr)
#pragma unroll
        for (int nr = 0; nr < 4; ++nr)
          acc[mr][nr] = mfma16(af[mr], bfr[nr], acc[mr][nr]);
    }
  }

#pragma unroll
  for (int nr = 0; nr < 4; ++nr) {
    const int col = tn * 128 + wn * 64 + nr * 16 + l15;
    float bv;
    int which = 0, c = col;
    if (EPI == 0) {
      which = col >> 10;
      c = col & 1023;
      const float* bp = (which == 0) ? bias : (which == 1) ? bias2 : bias3;
      bv = bp[c];
    } else {
      bv = bias[col];
    }
#pragma unroll
    for (int mr = 0; mr < 4; ++mr) {
#pragma unroll
      for (int j = 0; j < 4; ++j) {
        const int row = tm * 128 + wm * 64 + mr * 16 + lg * 4 + j;
        float v = acc[mr][nr][j] + bv;
        if (EPI == 0) {
          if (which == 0) v *= 0.125f;           // 1/sqrt(hd)
          const int b = row >> 11, s = row & 2047, h = c >> 6, hd = c & 63;
          bout[(size_t)which * 4194304 +
               (((size_t)(b * NH + h)) * S_LEN + s) * 64 + hd] = f2bf(v);
        } else {
          const float gl = 0.5f * v * (1.f + erff(v * 0.70710678118654752f));
          bout[(size_t)row * N + col] = f2bf(gl);
        }
      }
    }
  }
}

// ---------------------------------------------------------------------------
// GEMM 64x128, BK=64, DOUBLE-buffered (for N=1024 GEMMs: grid 512 = 2/CU).
// EPI 1: fp32 out = acc + bias + resf    (O-proj + residual x)
// EPI 3: fp32 out = acc + bias + bf2f(resb)  (FFN2 + residual sa)
// ---------------------------------------------------------------------------
template <int EPI>
__global__ __launch_bounds__(256) void gemm64(
    const unsigned short* __restrict__ A,
    const unsigned short* __restrict__ Bt,
    const float* __restrict__ bias,
    int N, int K,
    float* __restrict__ fout,
    const float* __restrict__ resf,
    const unsigned short* __restrict__ resb)
{
  __shared__ __align__(16) unsigned short As[2][64 * 64];
  __shared__ __align__(16) unsigned short Bs[2][128 * 64];
  const int tn = blockIdx.x, tm = blockIdx.y;
  const int tid = threadIdx.x;
  const int wid = tid >> 6, lane = tid & 63;
  const int wm = wid >> 1, wn = wid & 1;
  const int l15 = lane & 15, lg = lane >> 4;
  const int srow = lane >> 3, sk8 = (lane & 7) << 3;

  f32x4 acc[2][4];
#pragma unroll
  for (int i = 0; i < 2; ++i)
#pragma unroll
    for (int j = 0; j < 4; ++j) acc[i][j] = (f32x4){0.f, 0.f, 0.f, 0.f};

  const size_t abase = (size_t)(tm * 64) * K;
  const size_t bbase = (size_t)(tn * 128) * K;

  auto STAGE = [&](int bufn, int kk) {
#pragma unroll
    for (int s = 0; s < 2; ++s) {
      const int row = wid * 16 + s * 8 + srow;
      gload_lds16(A + abase + (size_t)row * K + kk + (sk8 ^ swz(row)),
                  &As[bufn][(wid * 16 + s * 8) * 64]);
    }
#pragma unroll
    for (int s = 0; s < 4; ++s) {
      const int row = wid * 32 + s * 8 + srow;
      gload_lds16(Bt + bbase + (size_t)row * K + kk + (sk8 ^ swz(row)),
                  &Bs[bufn][(wid * 32 + s * 8) * 64]);
    }
  };

  STAGE(0, 0);
  __syncthreads();
  int cur = 0;
  for (int kk = 0; kk < K; kk += 64) {
    if (kk + 64 < K) STAGE(cur ^ 1, kk + 64);
#pragma unroll
    for (int sub = 0; sub < 2; ++sub) {
      bf16x8 af[2], bfr[4];
#pragma unroll
      for (int mr = 0; mr < 2; ++mr) {
        const int row = wm * 32 + mr * 16 + l15;
        af[mr] = *(const bf16x8*)&As[cur][row * 64 + ((sub * 32 + lg * 8) ^ swz(row))];
      }
#pragma unroll
      for (int nr = 0; nr < 4; ++nr) {
        const int row = wn * 64 + nr * 16 + l15;
        bfr[nr] = *(const bf16x8*)&Bs[cur][row * 64 + ((sub * 32 + lg * 8) ^ swz(row))];
      }
#pragma unroll
      for (int mr = 0; mr < 2; ++mr)
#pragma unroll
        for (int nr = 0; nr < 4; ++nr)
          acc[mr][nr] = mfma16(af[mr], bfr[nr], acc[mr][nr]);
    }
    __syncthreads();
    cur ^= 1;
  }

#pragma unroll
  for (int nr = 0; nr < 4; ++nr) {
    const int col = tn * 128 + wn * 64 + nr * 16 + l15;
    const float bv = bias[col];
#pragma unroll
    for (int mr = 0; mr < 2; ++mr) {
#pragma unroll
      for (int j = 0; j < 4; ++j) {
        const int row = tm * 64 + wm * 32 + mr * 16 + lg * 4 + j;
        const float v = acc[mr][nr][j] + bv;
        if (EPI == 1) {
          fout[(size_t)row * N + col] = v + resf[(size_t)row * N + col];
        } else {
          fout[(size_t)row * N + col] = v + bf2f(resb[(size_t)row * N + col]);
        }
      }
    }
  }
}

// ---------------------------------------------------------------------------
// Flash attention fwd, swapped-QK^T softmax (lane-local q-rows).
// 1D grid 512 blocks XCD-grouped; 512 threads = 8 waves x 16 q-rows.
// S^T = mfma(K,Q): lane holds q = lane&15, kv = nr*16 + (lane>>4)*4 + j.
// Row-max: lane tree + 2 shfl.  P packed as b64 writes.  Defer-max THR=8.
// q,k: (bh,s,64);  vt: (bh,64,s);  ctx out: (token,1024) bf16.
// ---------------------------------------------------------------------------
__global__ __launch_bounds__(512) void attn_fwd(
    const unsigned short* __restrict__ qg,
    const unsigned short* __restrict__ kg,
    const unsigned short* __restrict__ vtg,
    const int* __restrict__ amask,
    unsigned short* __restrict__ ctx)
{
  __shared__ __align__(16) unsigned short Ks[2][64 * 64];
  __shared__ __align__(16) unsigned short Vs[2][64 * 64];   // [hd][kv]
  __shared__ __align__(16) unsigned short Ps[8][16 * 72];
  __shared__ __align__(16) int mk[2][64];

  const int bx = blockIdx.x;
  const int qt = (bx >> 3) & 15;
  const int bh = ((bx & 7) << 2) | (bx >> 7);
  const int b = bh >> 4, h = bh & 15;
  const int tid = threadIdx.x;
  const int wid = tid >> 6, lane = tid & 63;
  const int l15 = lane & 15, lg = lane >> 4;
  const int srow = lane >> 3, sk8 = (lane & 7) << 3;

  // Q as B-fragment: lane holds col q=l15, k=hd=lg*8+i
  const size_t qoff =
      (((size_t)bh * S_LEN) + qt * 128 + wid * 16 + l15) * 64 + lg * 8;
  const bf16x8 aq0 = *(const bf16x8*)&qg[qoff];
  const bf16x8 aq1 = *(const bf16x8*)&qg[qoff + 32];

  f32x4 o_[4];
#pragma unroll
  for (int n = 0; n < 4; ++n) o_[n] = (f32x4){0.f, 0.f, 0.f, 0.f};
  float mreg = -3e38f, lsum = 0.f;

  const size_t kbase  = (size_t)bh * (S_LEN * 64);
  const size_t vtbase = (size_t)bh * (64 * S_LEN);
  unsigned short* Pw = &Ps[wid][0];
  const int rk = wid * 8 + srow;           // staging row (8 rows/wave)
  const int swr = sk8 ^ swz(rk);

  auto STAGE = [&](int bufn, int t) {
    gload_lds16(kg + kbase + (size_t)(t * 64 + rk) * 64 + swr,
                &Ks[bufn][wid * 8 * 64]);
    gload_lds16(vtg + vtbase + (size_t)rk * S_LEN + t * 64 + swr,
                &Vs[bufn][wid * 8 * 64]);
    if (tid < 64) mk[bufn][tid] = amask[b * S_LEN + t * 64 + tid];
  };

  STAGE(0, 0);
  __syncthreads();
  int cur = 0;

  for (int t = 0; t < S_LEN / 64; ++t) {
    if (t + 1 < S_LEN / 64) STAGE(cur ^ 1, t + 1);

    // S^T = K·Q^T : C[row kv_local = lg*4+j][col q = l15]
    __builtin_amdgcn_s_setprio(1);
    f32x4 sf[4];
#pragma unroll
    for (int nr = 0; nr < 4; ++nr) {
      const int kvloc = nr * 16 + l15;
      const int e = swz(kvloc);
      const bf16x8 bk0 = *(const bf16x8*)&Ks[cur][kvloc * 64 + ((lg * 8) ^ e)];
      const bf16x8 bk1 = *(const bf16x8*)&Ks[cur][kvloc * 64 + ((32 + lg * 8) ^ e)];
      f32x4 a = (f32x4){0.f, 0.f, 0.f, 0.f};
      a = mfma16(bk0, aq0, a);
      a = mfma16(bk1, aq1, a);
      sf[nr] = a;
    }
    __builtin_amdgcn_s_setprio(0);

    // mask (kv = nr*16 + lg*4 + j); int4 broadcast reads
#pragma unroll
    for (int nr = 0; nr < 4; ++nr) {
      const int4 mki = *(const int4*)&mk[cur][nr * 16 + lg * 4];
      if (mki.x == 0) sf[nr][0] = -3e38f;
      if (mki.y == 0) sf[nr][1] = -3e38f;
      if (mki.z == 0) sf[nr][2] = -3e38f;
      if (mki.w == 0) sf[nr][3] = -3e38f;
    }

    // row max: lane-local tree over 16 + 2 shfl (4 lanes share a row)
    float pmax = fmaxf(fmaxf(fmaxf(sf[0][0], sf[0][1]), fmaxf(sf[0][2], sf[0][3])),
                       fmaxf(fmaxf(sf[1][0], sf[1][1]), fmaxf(sf[1][2], sf[1][3])));
    pmax = fmaxf(pmax,
           fmaxf(fmaxf(fmaxf(sf[2][0], sf[2][1]), fmaxf(sf[2][2], sf[2][3])),
                 fmaxf(fmaxf(sf[3][0], sf[3][1]), fmaxf(sf[3][2], sf[3][3]))));
    pmax = fmaxf(pmax, __shfl_xor(pmax, 16));
    pmax = fmaxf(pmax, __shfl_xor(pmax, 32));

    // defer-max: rescale only when the running max grew by > 8
    if (__any(pmax > mreg + 8.f)) {
      const float mn = fmaxf(mreg, pmax);
      const float sc = __expf(mreg - mn);
      mreg = mn;
      lsum *= sc;
      float scr[4];
#pragma unroll
      for (int j = 0; j < 4; ++j) scr[j] = __shfl(sc, lg * 4 + j);
#pragma unroll
      for (int n = 0; n < 4; ++n) {
        o_[n][0] *= scr[0]; o_[n][1] *= scr[1];
        o_[n][2] *= scr[2]; o_[n][3] *= scr[3];
      }
    }

    // P = exp(S - m), packed bf16 b64 stores (consecutive kv)
    asm volatile("s_waitcnt lgkmcnt(0)" ::: "memory");
#pragma unroll
    for (int nr = 0; nr < 4; ++nr) {
      const float p0 = __expf(sf[nr][0] - mreg);
      const float p1 = __expf(sf[nr][1] - mreg);
      const float p2 = __expf(sf[nr][2] - mreg);
      const float p3 = __expf(sf[nr][3] - mreg);
      lsum += (p0 + p1) + (p2 + p3);
      bf16x4v pk;
      pk[0] = (__bf16)p0; pk[1] = (__bf16)p1;
      pk[2] = (__bf16)p2; pk[3] = (__bf16)p3;
      *(bf16x4v*)&Pw[l15 * 72 + nr * 16 + lg * 4] = pk;
    }
    asm volatile("s_waitcnt lgkmcnt(0)" ::: "memory");

    // PV: A = P rows q, B = V^T  ->  o_ rows q = lg*4+j, col hd
    __builtin_amdgcn_s_setprio(1);
    {
      const bf16x8 pa0 = *(const bf16x8*)&Pw[l15 * 72 + lg * 8];
      const bf16x8 pa1 = *(const bf16x8*)&Pw[l15 * 72 + 32 + lg * 8];
#pragma unroll
      for (int n = 0; n < 4; ++n) {
        const int hd = n * 16 + l15;
        const int eh = swz(hd);
        const bf16x8 bv0 = *(const bf16x8*)&Vs[cur][hd * 64 + ((lg * 8) ^ eh)];
        const bf16x8 bv1 = *(const bf16x8*)&Vs[cur][hd * 64 + ((32 + lg * 8) ^ eh)];
        o_[n] = mfma16(pa0, bv0, o_[n]);
        o_[n] = mfma16(pa1, bv1, o_[n]);
      }
    }
    __builtin_amdgcn_s_setprio(0);
    __syncthreads();
    cur ^= 1;
  }

  // final: row-sum lives per lane (row q=l15); reduce over the 4 lg lanes
  lsum += __shfl_xor(lsum, 16);
  lsum += __shfl_xor(lsum, 32);
  const float rinv = 1.f / lsum;
  float rj[4];
#pragma unroll
  for (int j = 0; j < 4; ++j) rj[j] = __shfl(rinv, lg * 4 + j);
#pragma unroll
  for (int n = 0; n < 4; ++n) {
#pragma unroll
    for (int j = 0; j < 4; ++j) {
      const int sr = qt * 128 + wid * 16 + lg * 4 + j;
      const size_t idx = ((size_t)b * S_LEN + sr) * DIM_ + h * 64 + n * 16 + l15;
      ctx[idx] = f2bf(o_[n][j] * rj[j]);
    }
  }
}

// ---------------------------------------------------------------------------
// LayerNorm rows of 1024 fp32.  OUTBF=1 -> bf16 out, else fp32 (in-place ok).
// ---------------------------------------------------------------------------
template <int OUTBF>
__global__ __launch_bounds__(256) void ln_fused(
    const float* __restrict__ in, const float* __restrict__ g,
    const float* __restrict__ be,
    float* __restrict__ fout, unsigned short* __restrict__ bout)
{
  const int row = blockIdx.x, tid = threadIdx.x;
  const float4 v = ((const float4*)(in + (size_t)row * DIM_))[tid];
  float s = v.x + v.y + v.z + v.w;
  float s2 = v.x * v.x + v.y * v.y + v.z * v.z + v.w * v.w;
#pragma unroll
  for (int off = 1; off < 64; off <<= 1) {
    s += __shfl_xor(s, off);
    s2 += __shfl_xor(s2, off);
  }
  __shared__ float rs[4], rs2[4];
  if ((tid & 63) == 0) { rs[tid >> 6] = s; rs2[tid >> 6] = s2; }
  __syncthreads();
  s  = rs[0] + rs[1] + rs[2] + rs[3];
  s2 = rs2[0] + rs2[1] + rs2[2] + rs2[3];
  const float mean = s * (1.f / DIM_);
  const float var = fmaxf(s2 * (1.f / DIM_) - mean * mean, 0.f);
  const float inv = rsqrtf(var + 1e-12f);
  const float4 gv = ((const float4*)g)[tid];
  const float4 bv = ((const float4*)be)[tid];
  const float o0 = (v.x - mean) * inv * gv.x + bv.x;
  const float o1 = (v.y - mean) * inv * gv.y + bv.y;
  const float o2 = (v.z - mean) * inv * gv.z + bv.z;
  const float o3 = (v.w - mean) * inv * gv.w + bv.w;
  if (OUTBF) {
    ushort4 o = { f2bf(o0), f2bf(o1), f2bf(o2), f2bf(o3) };
    ((ushort4*)(bout + (size_t)row * DIM_))[tid] = o;
  } else {
    ((float4*)(fout + (size_t)row * DIM_))[tid] = make_float4(o0, o1, o2, o3);
  }
}

// ---------------------------------------------------------------------------
extern "C" void kernel_launch(void* const* d_in, const int* in_sizes, int n_in,
                              void* d_out, int out_size, void* d_ws, size_t ws_size,
                              hipStream_t stream)
{
  const float* x   = (const float*)d_in[0];
  const int* amask = (const int*)d_in[1];
  const float* Wq  = (const float*)d_in[2];
  const float* bq  = (const float*)d_in[3];
  const float* Wk  = (const float*)d_in[4];
  const float* bk  = (const float*)d_in[5];
  const float* Wv  = (const float*)d_in[6];
  const float* bv  = (const float*)d_in[7];
  const float* Wo  = (const float*)d_in[8];
  const float* bo  = (const float*)d_in[9];
  const float* g1  = (const float*)d_in[10];
  const float* be1 = (const float*)d_in[11];
  const float* W1  = (const float*)d_in[12];
  const float* b1  = (const float*)d_in[13];
  const float* W2  = (const float*)d_in[14];
  const float* b2  = (const float*)d_in[15];
  const float* g2  = (const float*)d_in[16];
  const float* be2 = (const float*)d_in[17];
  float* out = (float*)d_out;

  char* ws = (char*)d_ws;
  const size_t MB = (size_t)1 << 20;
  unsigned short* wqkvT = (unsigned short*)(ws + 0 * MB);   // [3072][1024]
  unsigned short* wqt = wqkvT;
  unsigned short* wkt = (unsigned short*)(ws + 2 * MB);
  unsigned short* wvt = (unsigned short*)(ws + 4 * MB);
  unsigned short* wot = (unsigned short*)(ws + 6 * MB);
  unsigned short* w1t = (unsigned short*)(ws + 8 * MB);
  unsigned short* w2t = (unsigned short*)(ws + 16 * MB);
  unsigned short* qb  = (unsigned short*)(ws + 24 * MB);    // q,k,v contiguous
  unsigned short* xb  = (unsigned short*)(ws + 48 * MB);
  unsigned short* vtb = (unsigned short*)(ws + 48 * MB);    // vt (after xb dead)
  unsigned short* ctx = (unsigned short*)(ws + 56 * MB);
  unsigned short* sab = qb;                                  // reuse after attn
  unsigned short* hb  = (unsigned short*)(ws + 32 * MB);     // reuse [32,64)
  float* preln = out;                                        // d_out as scratch

  trans_cvt<<<dim3(16, 16), 256, 0, stream>>>(Wq, wqt, 1024, 1024);
  trans_cvt<<<dim3(16, 16), 256, 0, stream>>>(Wk, wkt, 1024, 1024);
  trans_cvt<<<dim3(16, 16), 256, 0, stream>>>(Wv, wvt, 1024, 1024);
  trans_cvt<<<dim3(16, 16), 256, 0, stream>>>(Wo, wot, 1024, 1024);
  trans_cvt<<<dim3(64, 16), 256, 0, stream>>>(W1, w1t, 1024, 4096);
  trans_cvt<<<dim3(16, 64), 256, 0, stream>>>(W2, w2t, 4096, 1024);
  cvt_bf16<<<4096, 256, 0, stream>>>(x, xb, 4096 * 1024 / 4);

  // fused QKV projection (N=3072), scatter to (bh,s,hd)
  gemm_bt<0><<<dim3(24, 32), 256, 0, stream>>>(xb, wqkvT, bq, bk, bv,
      3072, 1024, qb);

  // V -> Vt (bh,64,s); xb is dead now
  trans_v<<<dim3(32, 32), 256, 0, stream>>>(qb + 2 * 4194304, vtb);

  // attention (XCD-grouped 1D grid)
  attn_fwd<<<512, 512, 0, stream>>>(qb, qb + 4194304, vtb, amask, ctx);

  // O-proj + bias + residual(x) -> preln (d_out)
  gemm64<1><<<dim3(8, 64), 256, 0, stream>>>(ctx, wot, bo, 1024, 1024,
      preln, x, nullptr);
  ln_fused<1><<<4096, 256, 0, stream>>>(preln, g1, be1, nullptr, sab);

  // FFN
  gemm_bt<2><<<dim3(32, 32), 256, 0, stream>>>(sab, w1t, b1, nullptr, nullptr,
      4096, 1024, hb);
  gemm64<3><<<dim3(8, 64), 256, 0, stream>>>(hb, w2t, b2, 1024, 4096,
      preln, nullptr, sab);
  ln_fused<0><<<4096, 256, 0, stream>>>(preln, g2, be2, out, nullptr);
}

// Round 9
// 379.853 us; speedup vs baseline: 1.2848x; 1.0410x over previous
//
#include <hip/hip_runtime.h>

// ---------------------------------------------------------------------------
// TransformerBlock on MI355X (gfx950).  B=2, S=2048, D=1024, H=16, hd=64,
// HIDDEN=4096.  bf16 MFMA (16x16x32), fp32 accum/softmax/LN.
// All GEMMs: 64x128 tile, BK=64, double-buffered LDS (2-phase pipeline).
// Workspace (MiB): [0,6) WqkvT  [6,8) WoT  [8,16) W1T  [16,24) W2T
//   [24,32) q (later sab)  [32,40) k  [40,48) v  [48,56) xb (later vt)
//   [56,64) ctx ; [32,64) later reused as h (FFN hidden bf16)
// d_out doubles as fp32 pre-LN scratch. Total 64 MiB.
// ---------------------------------------------------------------------------

typedef __bf16 bf16x8 __attribute__((ext_vector_type(8)));
typedef __bf16 bf16x4v __attribute__((ext_vector_type(4)));
typedef float f32x4 __attribute__((ext_vector_type(4)));

#define DIM_ 1024
#define S_LEN 2048
#define NH 16

__device__ __forceinline__ unsigned short f2bf(float f) {
  unsigned u = __float_as_uint(f);
  u = (u + 0x7FFFu + ((u >> 16) & 1u)) >> 16;   // RNE
  return (unsigned short)u;
}
__device__ __forceinline__ float bf2f(unsigned short h) {
  return __uint_as_float(((unsigned)h) << 16);
}
__device__ __forceinline__ f32x4 mfma16(bf16x8 a, bf16x8 b, f32x4 c) {
  return __builtin_amdgcn_mfma_f32_16x16x32_bf16(a, b, c, 0, 0, 0);
}
__device__ __forceinline__ void gload_lds16(const void* g, void* l) {
  __builtin_amdgcn_global_load_lds(
      (const __attribute__((address_space(1))) void*)g,
      (__attribute__((address_space(3))) void*)l, 16, 0, 0);
}
__device__ __forceinline__ int swz(int row) { return ((row ^ (row >> 3)) & 7) << 3; }

// ---------------------------------------------------------------------------
// 4x 1024x1024: W[K][N] fp32 -> Wt[N][K] bf16 (z-indexed, one launch)
// ---------------------------------------------------------------------------
__global__ __launch_bounds__(256) void trans_cvt4(
    const float* __restrict__ Wa, const float* __restrict__ Wb,
    const float* __restrict__ Wc, const float* __restrict__ Wd,
    unsigned short* __restrict__ Ta, unsigned short* __restrict__ Tb,
    unsigned short* __restrict__ Tc, unsigned short* __restrict__ Td)
{
  const int z = blockIdx.z;
  const float* W = (z == 0) ? Wa : (z == 1) ? Wb : (z == 2) ? Wc : Wd;
  unsigned short* Wt = (z == 0) ? Ta : (z == 1) ? Tb : (z == 2) ? Tc : Td;
  const int K = 1024, N = 1024;
  __shared__ float tile[64][65];
  const int n0 = blockIdx.x * 64, k0 = blockIdx.y * 64;
  const int tid = threadIdx.x;
  const int tr = tid >> 4, tc = (tid & 15) << 2;
#pragma unroll
  for (int rr = 0; rr < 64; rr += 16) {
    const float4 v = *(const float4*)&W[(size_t)(k0 + tr + rr) * N + n0 + tc];
    tile[tr + rr][tc + 0] = v.x; tile[tr + rr][tc + 1] = v.y;
    tile[tr + rr][tc + 2] = v.z; tile[tr + rr][tc + 3] = v.w;
  }
  __syncthreads();
#pragma unroll
  for (int nn = 0; nn < 64; nn += 16) {
    const int n = tr + nn;
    ushort4 o;
    o.x = f2bf(tile[tc + 0][n]);
    o.y = f2bf(tile[tc + 1][n]);
    o.z = f2bf(tile[tc + 2][n]);
    o.w = f2bf(tile[tc + 3][n]);
    *(ushort4*)&Wt[(size_t)(n0 + n) * K + k0 + tc] = o;
  }
}

// W[K][N] fp32 -> Wt[N][K] bf16 (generic, for W1/W2)
__global__ __launch_bounds__(256) void trans_cvt(
    const float* __restrict__ W, unsigned short* __restrict__ Wt, int K, int N)
{
  __shared__ float tile[64][65];
  const int n0 = blockIdx.x * 64, k0 = blockIdx.y * 64;
  const int tid = threadIdx.x;
  const int tr = tid >> 4, tc = (tid & 15) << 2;
#pragma unroll
  for (int rr = 0; rr < 64; rr += 16) {
    const float4 v = *(const float4*)&W[(size_t)(k0 + tr + rr) * N + n0 + tc];
    tile[tr + rr][tc + 0] = v.x; tile[tr + rr][tc + 1] = v.y;
    tile[tr + rr][tc + 2] = v.z; tile[tr + rr][tc + 3] = v.w;
  }
  __syncthreads();
#pragma unroll
  for (int nn = 0; nn < 64; nn += 16) {
    const int n = tr + nn;
    ushort4 o;
    o.x = f2bf(tile[tc + 0][n]);
    o.y = f2bf(tile[tc + 1][n]);
    o.z = f2bf(tile[tc + 2][n]);
    o.w = f2bf(tile[tc + 3][n]);
    *(ushort4*)&Wt[(size_t)(n0 + n) * K + k0 + tc] = o;
  }
}

__global__ void cvt_bf16(const float* __restrict__ in,
                         unsigned short* __restrict__ out, int n4)
{
  const int i = blockIdx.x * blockDim.x + threadIdx.x;
  if (i >= n4) return;
  const float4 v = ((const float4*)in)[i];
  ushort4 o = { f2bf(v.x), f2bf(v.y), f2bf(v.z), f2bf(v.w) };
  ((ushort4*)out)[i] = o;
}

// ---------------------------------------------------------------------------
// V (bh,s,64) bf16 -> Vt (bh,64,s) bf16
// ---------------------------------------------------------------------------
__global__ __launch_bounds__(256) void trans_v(
    const unsigned short* __restrict__ v, unsigned short* __restrict__ vt)
{
  __shared__ unsigned short tile[64][66];
  const int st = blockIdx.x, bh = blockIdx.y;
  const int tid = threadIdx.x;
  const int r = tid >> 3, c = (tid & 7) << 3;
  const size_t base = (size_t)bh * (S_LEN * 64);
#pragma unroll
  for (int p = 0; p < 2; ++p) {
    const int s = r + p * 32;
    const uint4 raw = *(const uint4*)(v + base + (size_t)(st * 64 + s) * 64 + c);
    const unsigned short* pr = (const unsigned short*)&raw;
#pragma unroll
    for (int j = 0; j < 8; ++j) tile[s][c + j] = pr[j];
  }
  __syncthreads();
#pragma unroll
  for (int p = 0; p < 2; ++p) {
    const int hd = r + p * 32;
    ushort4 o[2];
#pragma unroll
    for (int j = 0; j < 8; ++j) ((unsigned short*)o)[j] = tile[c + j][hd];
    *(uint4*)(vt + (size_t)bh * (64 * S_LEN) + (size_t)hd * S_LEN + st * 64 + c) =
        *(const uint4*)o;
  }
}

// ---------------------------------------------------------------------------
// Unified GEMM: C[M][N] = A[M][K] * Bt[N][K]^T.  64x128 tile, BK=64,
// double-buffered LDS (prefetch-before-compute, one barrier per K-step).
// EPI 0: QKV scatter to (bh,s,hd) bf16 (col>>10 picks q/k/v; q scaled 1/8)
// EPI 1: fp32 out = acc + bias + resf              (O-proj + residual x)
// EPI 2: bf16 out = gelu(acc + bias)               (FFN1 hidden)
// EPI 3: fp32 out = acc + bias + bf2f(resb)        (FFN2 + residual sa)
// ---------------------------------------------------------------------------
template <int EPI>
__global__ __launch_bounds__(256) void gemmdb(
    const unsigned short* __restrict__ A,
    const unsigned short* __restrict__ Bt,
    const float* __restrict__ bias,
    const float* __restrict__ bias2,
    const float* __restrict__ bias3,
    int N, int K,
    float* __restrict__ fout,
    unsigned short* __restrict__ bout,
    const float* __restrict__ resf,
    const unsigned short* __restrict__ resb)
{
  __shared__ __align__(16) unsigned short As[2][64 * 64];
  __shared__ __align__(16) unsigned short Bs[2][128 * 64];
  const int tn = blockIdx.x, tm = blockIdx.y;
  const int tid = threadIdx.x;
  const int wid = tid >> 6, lane = tid & 63;
  const int wm = wid >> 1, wn = wid & 1;
  const int l15 = lane & 15, lg = lane >> 4;
  const int srow = lane >> 3, sk8 = (lane & 7) << 3;

  f32x4 acc[2][4];
#pragma unroll
  for (int i = 0; i < 2; ++i)
#pragma unroll
    for (int j = 0; j < 4; ++j) acc[i][j] = (f32x4){0.f, 0.f, 0.f, 0.f};

  const size_t abase = (size_t)(tm * 64) * K;
  const size_t bbase = (size_t)(tn * 128) * K;

  auto STAGE = [&](int bufn, int kk) {
#pragma unroll
    for (int s = 0; s < 2; ++s) {
      const int row = wid * 16 + s * 8 + srow;
      gload_lds16(A + abase + (size_t)row * K + kk + (sk8 ^ swz(row)),
                  &As[bufn][(wid * 16 + s * 8) * 64]);
    }
#pragma unroll
    for (int s = 0; s < 4; ++s) {
      const int row = wid * 32 + s * 8 + srow;
      gload_lds16(Bt + bbase + (size_t)row * K + kk + (sk8 ^ swz(row)),
                  &Bs[bufn][(wid * 32 + s * 8) * 64]);
    }
  };

  STAGE(0, 0);
  __syncthreads();
  int cur = 0;
  for (int kk = 0; kk < K; kk += 64) {
    if (kk + 64 < K) STAGE(cur ^ 1, kk + 64);
#pragma unroll
    for (int sub = 0; sub < 2; ++sub) {
      bf16x8 af[2], bfr[4];
#pragma unroll
      for (int mr = 0; mr < 2; ++mr) {
        const int row = wm * 32 + mr * 16 + l15;
        af[mr] = *(const bf16x8*)&As[cur][row * 64 + ((sub * 32 + lg * 8) ^ swz(row))];
      }
#pragma unroll
      for (int nr = 0; nr < 4; ++nr) {
        const int row = wn * 64 + nr * 16 + l15;
        bfr[nr] = *(const bf16x8*)&Bs[cur][row * 64 + ((sub * 32 + lg * 8) ^ swz(row))];
      }
#pragma unroll
      for (int mr = 0; mr < 2; ++mr)
#pragma unroll
        for (int nr = 0; nr < 4; ++nr)
          acc[mr][nr] = mfma16(af[mr], bfr[nr], acc[mr][nr]);
    }
    __syncthreads();
    cur ^= 1;
  }

  // epilogue; C layout: col = lane&15, row = (lane>>4)*4 + reg
#pragma unroll
  for (int nr = 0; nr < 4; ++nr) {
    const int col = tn * 128 + wn * 64 + nr * 16 + l15;
    float bv;
    int which = 0, c = col;
    if (EPI == 0) {
      which = col >> 10;
      c = col & 1023;
      const float* bp = (which == 0) ? bias : (which == 1) ? bias2 : bias3;
      bv = bp[c];
    } else {
      bv = bias[col];
    }
#pragma unroll
    for (int mr = 0; mr < 2; ++mr) {
#pragma unroll
      for (int j = 0; j < 4; ++j) {
        const int row = tm * 64 + wm * 32 + mr * 16 + lg * 4 + j;
        float v = acc[mr][nr][j] + bv;
        if (EPI == 0) {
          if (which == 0) v *= 0.125f;           // 1/sqrt(hd)
          const int b = row >> 11, s = row & 2047, h = c >> 6, hd = c & 63;
          bout[(size_t)which * 4194304 +
               (((size_t)(b * NH + h)) * S_LEN + s) * 64 + hd] = f2bf(v);
        } else if (EPI == 1) {
          fout[(size_t)row * N + col] = v + resf[(size_t)row * N + col];
        } else if (EPI == 2) {
          const float gl = 0.5f * v * (1.f + erff(v * 0.70710678118654752f));
          bout[(size_t)row * N + col] = f2bf(gl);
        } else {
          fout[(size_t)row * N + col] = v + bf2f(resb[(size_t)row * N + col]);
        }
      }
    }
  }
}

// ---------------------------------------------------------------------------
// Flash attention fwd, swapped-QK^T softmax (lane-local q-rows).
// 1D grid 512 blocks XCD-grouped; 512 threads = 8 waves x 16 q-rows.
// S^T = mfma(K,Q): lane holds q = lane&15, kv = nr*16 + (lane>>4)*4 + j.
// Row-max: lane tree + 2 shfl.  P packed as b64 writes.  Defer-max THR=8.
// q,k: (bh,s,64);  vt: (bh,64,s);  ctx out: (token,1024) bf16.
// ---------------------------------------------------------------------------
__global__ __launch_bounds__(512) void attn_fwd(
    const unsigned short* __restrict__ qg,
    const unsigned short* __restrict__ kg,
    const unsigned short* __restrict__ vtg,
    const int* __restrict__ amask,
    unsigned short* __restrict__ ctx)
{
  __shared__ __align__(16) unsigned short Ks[2][64 * 64];
  __shared__ __align__(16) unsigned short Vs[2][64 * 64];   // [hd][kv]
  __shared__ __align__(16) unsigned short Ps[8][16 * 72];
  __shared__ __align__(16) int mk[2][64];

  const int bx = blockIdx.x;
  const int qt = (bx >> 3) & 15;
  const int bh = ((bx & 7) << 2) | (bx >> 7);
  const int b = bh >> 4, h = bh & 15;
  const int tid = threadIdx.x;
  const int wid = tid >> 6, lane = tid & 63;
  const int l15 = lane & 15, lg = lane >> 4;
  const int srow = lane >> 3, sk8 = (lane & 7) << 3;

  // Q as B-fragment: lane holds col q=l15, k=hd=lg*8+i
  const size_t qoff =
      (((size_t)bh * S_LEN) + qt * 128 + wid * 16 + l15) * 64 + lg * 8;
  const bf16x8 aq0 = *(const bf16x8*)&qg[qoff];
  const bf16x8 aq1 = *(const bf16x8*)&qg[qoff + 32];

  f32x4 o_[4];
#pragma unroll
  for (int n = 0; n < 4; ++n) o_[n] = (f32x4){0.f, 0.f, 0.f, 0.f};
  float mreg = -3e38f, lsum = 0.f;

  const size_t kbase  = (size_t)bh * (S_LEN * 64);
  const size_t vtbase = (size_t)bh * (64 * S_LEN);
  unsigned short* Pw = &Ps[wid][0];
  const int rk = wid * 8 + srow;           // staging row (8 rows/wave)
  const int swr = sk8 ^ swz(rk);

  auto STAGE = [&](int bufn, int t) {
    gload_lds16(kg + kbase + (size_t)(t * 64 + rk) * 64 + swr,
                &Ks[bufn][wid * 8 * 64]);
    gload_lds16(vtg + vtbase + (size_t)rk * S_LEN + t * 64 + swr,
                &Vs[bufn][wid * 8 * 64]);
    if (tid < 64) mk[bufn][tid] = amask[b * S_LEN + t * 64 + tid];
  };

  STAGE(0, 0);
  __syncthreads();
  int cur = 0;

  for (int t = 0; t < S_LEN / 64; ++t) {
    if (t + 1 < S_LEN / 64) STAGE(cur ^ 1, t + 1);

    // S^T = K·Q^T : C[row kv_local = lg*4+j][col q = l15]
    __builtin_amdgcn_s_setprio(1);
    f32x4 sf[4];
#pragma unroll
    for (int nr = 0; nr < 4; ++nr) {
      const int kvloc = nr * 16 + l15;
      const int e = swz(kvloc);
      const bf16x8 bk0 = *(const bf16x8*)&Ks[cur][kvloc * 64 + ((lg * 8) ^ e)];
      const bf16x8 bk1 = *(const bf16x8*)&Ks[cur][kvloc * 64 + ((32 + lg * 8) ^ e)];
      f32x4 a = (f32x4){0.f, 0.f, 0.f, 0.f};
      a = mfma16(bk0, aq0, a);
      a = mfma16(bk1, aq1, a);
      sf[nr] = a;
    }
    __builtin_amdgcn_s_setprio(0);

    // mask (kv = nr*16 + lg*4 + j); int4 broadcast reads
#pragma unroll
    for (int nr = 0; nr < 4; ++nr) {
      const int4 mki = *(const int4*)&mk[cur][nr * 16 + lg * 4];
      if (mki.x == 0) sf[nr][0] = -3e38f;
      if (mki.y == 0) sf[nr][1] = -3e38f;
      if (mki.z == 0) sf[nr][2] = -3e38f;
      if (mki.w == 0) sf[nr][3] = -3e38f;
    }

    // row max: lane-local tree over 16 + 2 shfl (4 lanes share a row)
    float pmax = fmaxf(fmaxf(fmaxf(sf[0][0], sf[0][1]), fmaxf(sf[0][2], sf[0][3])),
                       fmaxf(fmaxf(sf[1][0], sf[1][1]), fmaxf(sf[1][2], sf[1][3])));
    pmax = fmaxf(pmax,
           fmaxf(fmaxf(fmaxf(sf[2][0], sf[2][1]), fmaxf(sf[2][2], sf[2][3])),
                 fmaxf(fmaxf(sf[3][0], sf[3][1]), fmaxf(sf[3][2], sf[3][3]))));
    pmax = fmaxf(pmax, __shfl_xor(pmax, 16));
    pmax = fmaxf(pmax, __shfl_xor(pmax, 32));

    // defer-max: rescale only when the running max grew by > 8
    if (__any(pmax > mreg + 8.f)) {
      const float mn = fmaxf(mreg, pmax);
      const float sc = __expf(mreg - mn);
      mreg = mn;
      lsum *= sc;
      float scr[4];
#pragma unroll
      for (int j = 0; j < 4; ++j) scr[j] = __shfl(sc, lg * 4 + j);
#pragma unroll
      for (int n = 0; n < 4; ++n) {
        o_[n][0] *= scr[0]; o_[n][1] *= scr[1];
        o_[n][2] *= scr[2]; o_[n][3] *= scr[3];
      }
    }

    // P = exp(S - m), packed bf16 b64 stores (consecutive kv)
    asm volatile("s_waitcnt lgkmcnt(0)" ::: "memory");
#pragma unroll
    for (int nr = 0; nr < 4; ++nr) {
      const float p0 = __expf(sf[nr][0] - mreg);
      const float p1 = __expf(sf[nr][1] - mreg);
      const float p2 = __expf(sf[nr][2] - mreg);
      const float p3 = __expf(sf[nr][3] - mreg);
      lsum += (p0 + p1) + (p2 + p3);
      bf16x4v pk;
      pk[0] = (__bf16)p0; pk[1] = (__bf16)p1;
      pk[2] = (__bf16)p2; pk[3] = (__bf16)p3;
      *(bf16x4v*)&Pw[l15 * 72 + nr * 16 + lg * 4] = pk;
    }
    asm volatile("s_waitcnt lgkmcnt(0)" ::: "memory");

    // PV: A = P rows q, B = V^T  ->  o_ rows q = lg*4+j, col hd
    __builtin_amdgcn_s_setprio(1);
    {
      const bf16x8 pa0 = *(const bf16x8*)&Pw[l15 * 72 + lg * 8];
      const bf16x8 pa1 = *(const bf16x8*)&Pw[l15 * 72 + 32 + lg * 8];
#pragma unroll
      for (int n = 0; n < 4; ++n) {
        const int hd = n * 16 + l15;
        const int eh = swz(hd);
        const bf16x8 bv0 = *(const bf16x8*)&Vs[cur][hd * 64 + ((lg * 8) ^ eh)];
        const bf16x8 bv1 = *(const bf16x8*)&Vs[cur][hd * 64 + ((32 + lg * 8) ^ eh)];
        o_[n] = mfma16(pa0, bv0, o_[n]);
        o_[n] = mfma16(pa1, bv1, o_[n]);
      }
    }
    __builtin_amdgcn_s_setprio(0);
    __syncthreads();
    cur ^= 1;
  }

  // final: row-sum lives per lane (row q=l15); reduce over the 4 lg lanes
  lsum += __shfl_xor(lsum, 16);
  lsum += __shfl_xor(lsum, 32);
  const float rinv = 1.f / lsum;
  float rj[4];
#pragma unroll
  for (int j = 0; j < 4; ++j) rj[j] = __shfl(rinv, lg * 4 + j);
#pragma unroll
  for (int n = 0; n < 4; ++n) {
#pragma unroll
    for (int j = 0; j < 4; ++j) {
      const int sr = qt * 128 + wid * 16 + lg * 4 + j;
      const size_t idx = ((size_t)b * S_LEN + sr) * DIM_ + h * 64 + n * 16 + l15;
      ctx[idx] = f2bf(o_[n][j] * rj[j]);
    }
  }
}

// ---------------------------------------------------------------------------
// LayerNorm rows of 1024 fp32.  OUTBF=1 -> bf16 out, else fp32 (in-place ok).
// ---------------------------------------------------------------------------
template <int OUTBF>
__global__ __launch_bounds__(256) void ln_fused(
    const float* __restrict__ in, const float* __restrict__ g,
    const float* __restrict__ be,
    float* __restrict__ fout, unsigned short* __restrict__ bout)
{
  const int row = blockIdx.x, tid = threadIdx.x;
  const float4 v = ((const float4*)(in + (size_t)row * DIM_))[tid];
  float s = v.x + v.y + v.z + v.w;
  float s2 = v.x * v.x + v.y * v.y + v.z * v.z + v.w * v.w;
#pragma unroll
  for (int off = 1; off < 64; off <<= 1) {
    s += __shfl_xor(s, off);
    s2 += __shfl_xor(s2, off);
  }
  __shared__ float rs[4], rs2[4];
  if ((tid & 63) == 0) { rs[tid >> 6] = s; rs2[tid >> 6] = s2; }
  __syncthreads();
  s  = rs[0] + rs[1] + rs[2] + rs[3];
  s2 = rs2[0] + rs2[1] + rs2[2] + rs2[3];
  const float mean = s * (1.f / DIM_);
  const float var = fmaxf(s2 * (1.f / DIM_) - mean * mean, 0.f);
  const float inv = rsqrtf(var + 1e-12f);
  const float4 gv = ((const float4*)g)[tid];
  const float4 bv = ((const float4*)be)[tid];
  const float o0 = (v.x - mean) * inv * gv.x + bv.x;
  const float o1 = (v.y - mean) * inv * gv.y + bv.y;
  const float o2 = (v.z - mean) * inv * gv.z + bv.z;
  const float o3 = (v.w - mean) * inv * gv.w + bv.w;
  if (OUTBF) {
    ushort4 o = { f2bf(o0), f2bf(o1), f2bf(o2), f2bf(o3) };
    ((ushort4*)(bout + (size_t)row * DIM_))[tid] = o;
  } else {
    ((float4*)(fout + (size_t)row * DIM_))[tid] = make_float4(o0, o1, o2, o3);
  }
}

// ---------------------------------------------------------------------------
extern "C" void kernel_launch(void* const* d_in, const int* in_sizes, int n_in,
                              void* d_out, int out_size, void* d_ws, size_t ws_size,
                              hipStream_t stream)
{
  const float* x   = (const float*)d_in[0];
  const int* amask = (const int*)d_in[1];
  const float* Wq  = (const float*)d_in[2];
  const float* bq  = (const float*)d_in[3];
  const float* Wk  = (const float*)d_in[4];
  const float* bk  = (const float*)d_in[5];
  const float* Wv  = (const float*)d_in[6];
  const float* bv  = (const float*)d_in[7];
  const float* Wo  = (const float*)d_in[8];
  const float* bo  = (const float*)d_in[9];
  const float* g1  = (const float*)d_in[10];
  const float* be1 = (const float*)d_in[11];
  const float* W1  = (const float*)d_in[12];
  const float* b1  = (const float*)d_in[13];
  const float* W2  = (const float*)d_in[14];
  const float* b2  = (const float*)d_in[15];
  const float* g2  = (const float*)d_in[16];
  const float* be2 = (const float*)d_in[17];
  float* out = (float*)d_out;

  char* ws = (char*)d_ws;
  const size_t MB = (size_t)1 << 20;
  unsigned short* wqkvT = (unsigned short*)(ws + 0 * MB);   // [3072][1024]
  unsigned short* wqt = wqkvT;
  unsigned short* wkt = (unsigned short*)(ws + 2 * MB);
  unsigned short* wvt = (unsigned short*)(ws + 4 * MB);
  unsigned short* wot = (unsigned short*)(ws + 6 * MB);
  unsigned short* w1t = (unsigned short*)(ws + 8 * MB);
  unsigned short* w2t = (unsigned short*)(ws + 16 * MB);
  unsigned short* qb  = (unsigned short*)(ws + 24 * MB);    // q,k,v contiguous
  unsigned short* xb  = (unsigned short*)(ws + 48 * MB);
  unsigned short* vtb = (unsigned short*)(ws + 48 * MB);    // vt (after xb dead)
  unsigned short* ctx = (unsigned short*)(ws + 56 * MB);
  unsigned short* sab = qb;                                  // reuse after attn
  unsigned short* hb  = (unsigned short*)(ws + 32 * MB);     // reuse [32,64)
  float* preln = out;                                        // d_out as scratch

  trans_cvt4<<<dim3(16, 16, 4), 256, 0, stream>>>(Wq, Wk, Wv, Wo,
                                                  wqt, wkt, wvt, wot);
  trans_cvt<<<dim3(64, 16), 256, 0, stream>>>(W1, w1t, 1024, 4096);
  trans_cvt<<<dim3(16, 64), 256, 0, stream>>>(W2, w2t, 4096, 1024);
  cvt_bf16<<<4096, 256, 0, stream>>>(x, xb, 4096 * 1024 / 4);

  // fused QKV projection (N=3072), scatter to (bh,s,hd)
  gemmdb<0><<<dim3(24, 64), 256, 0, stream>>>(xb, wqkvT, bq, bk, bv,
      3072, 1024, nullptr, qb, nullptr, nullptr);

  // V -> Vt (bh,64,s); xb is dead now
  trans_v<<<dim3(32, 32), 256, 0, stream>>>(qb + 2 * 4194304, vtb);

  // attention (XCD-grouped 1D grid)
  attn_fwd<<<512, 512, 0, stream>>>(qb, qb + 4194304, vtb, amask, ctx);

  // O-proj + bias + residual(x) -> preln (d_out)
  gemmdb<1><<<dim3(8, 64), 256, 0, stream>>>(ctx, wot, bo, nullptr, nullptr,
      1024, 1024, preln, nullptr, x, nullptr);
  ln_fused<1><<<4096, 256, 0, stream>>>(preln, g1, be1, nullptr, sab);

  // FFN
  gemmdb<2><<<dim3(32, 64), 256, 0, stream>>>(sab, w1t, b1, nullptr, nullptr,
      4096, 1024, nullptr, hb, nullptr, nullptr);
  gemmdb<3><<<dim3(8, 64), 256, 0, stream>>>(hb, w2t, b2, nullptr, nullptr,
      1024, 4096, preln, nullptr, nullptr, sab);
  ln_fused<0><<<4096, 256, 0, stream>>>(preln, g2, be2, out, nullptr);
}

// Round 11
// 374.587 us; speedup vs baseline: 1.3029x; 1.0141x over previous
//
#include <hip/hip_runtime.h>

// ---------------------------------------------------------------------------
// TransformerBlock on MI355X (gfx950).  B=2, S=2048, D=1024, H=16, hd=64,
// HIDDEN=4096.  bf16 MFMA (16x16x32), fp32 accum/softmax/LN.
// GEMMs: QKV/FFN1 = 128x128 dbuf tile; O-proj/FFN2 = 64x128 dbuf tile.
// Workspace (MiB): [0,6) WqkvT  [6,8) WoT  [8,16) W1T  [16,24) W2T
//   [24,32) q (later sab)  [32,40) k  [40,48) v  [48,56) xb (later vt)
//   [56,64) ctx ; [32,64) later reused as h (FFN hidden bf16)
// d_out doubles as fp32 pre-LN scratch. Total 64 MiB.
// ---------------------------------------------------------------------------

typedef __bf16 bf16x8 __attribute__((ext_vector_type(8)));
typedef __bf16 bf16x4v __attribute__((ext_vector_type(4)));
typedef float f32x4 __attribute__((ext_vector_type(4)));

#define DIM_ 1024
#define S_LEN 2048
#define NH 16

__device__ __forceinline__ unsigned short f2bf(float f) {
  unsigned u = __float_as_uint(f);
  u = (u + 0x7FFFu + ((u >> 16) & 1u)) >> 16;   // RNE
  return (unsigned short)u;
}
__device__ __forceinline__ float bf2f(unsigned short h) {
  return __uint_as_float(((unsigned)h) << 16);
}
__device__ __forceinline__ f32x4 mfma16(bf16x8 a, bf16x8 b, f32x4 c) {
  return __builtin_amdgcn_mfma_f32_16x16x32_bf16(a, b, c, 0, 0, 0);
}
__device__ __forceinline__ void gload_lds16(const void* g, void* l) {
  __builtin_amdgcn_global_load_lds(
      (const __attribute__((address_space(1))) void*)g,
      (__attribute__((address_space(3))) void*)l, 16, 0, 0);
}
__device__ __forceinline__ int swz(int row) { return ((row ^ (row >> 3)) & 7) << 3; }

// ---------------------------------------------------------------------------
// 4x 1024x1024: W[K][N] fp32 -> Wt[N][K] bf16 (z-indexed, one launch)
// ---------------------------------------------------------------------------
__global__ __launch_bounds__(256) void trans_cvt4(
    const float* __restrict__ Wa, const float* __restrict__ Wb,
    const float* __restrict__ Wc, const float* __restrict__ Wd,
    unsigned short* __restrict__ Ta, unsigned short* __restrict__ Tb,
    unsigned short* __restrict__ Tc, unsigned short* __restrict__ Td)
{
  const int z = blockIdx.z;
  const float* W = (z == 0) ? Wa : (z == 1) ? Wb : (z == 2) ? Wc : Wd;
  unsigned short* Wt = (z == 0) ? Ta : (z == 1) ? Tb : (z == 2) ? Tc : Td;
  const int K = 1024, N = 1024;
  __shared__ float tile[64][65];
  const int n0 = blockIdx.x * 64, k0 = blockIdx.y * 64;
  const int tid = threadIdx.x;
  const int tr = tid >> 4, tc = (tid & 15) << 2;
#pragma unroll
  for (int rr = 0; rr < 64; rr += 16) {
    const float4 v = *(const float4*)&W[(size_t)(k0 + tr + rr) * N + n0 + tc];
    tile[tr + rr][tc + 0] = v.x; tile[tr + rr][tc + 1] = v.y;
    tile[tr + rr][tc + 2] = v.z; tile[tr + rr][tc + 3] = v.w;
  }
  __syncthreads();
#pragma unroll
  for (int nn = 0; nn < 64; nn += 16) {
    const int n = tr + nn;
    ushort4 o;
    o.x = f2bf(tile[tc + 0][n]);
    o.y = f2bf(tile[tc + 1][n]);
    o.z = f2bf(tile[tc + 2][n]);
    o.w = f2bf(tile[tc + 3][n]);
    *(ushort4*)&Wt[(size_t)(n0 + n) * K + k0 + tc] = o;
  }
}

// W[K][N] fp32 -> Wt[N][K] bf16 (generic, for W1/W2)
__global__ __launch_bounds__(256) void trans_cvt(
    const float* __restrict__ W, unsigned short* __restrict__ Wt, int K, int N)
{
  __shared__ float tile[64][65];
  const int n0 = blockIdx.x * 64, k0 = blockIdx.y * 64;
  const int tid = threadIdx.x;
  const int tr = tid >> 4, tc = (tid & 15) << 2;
#pragma unroll
  for (int rr = 0; rr < 64; rr += 16) {
    const float4 v = *(const float4*)&W[(size_t)(k0 + tr + rr) * N + n0 + tc];
    tile[tr + rr][tc + 0] = v.x; tile[tr + rr][tc + 1] = v.y;
    tile[tr + rr][tc + 2] = v.z; tile[tr + rr][tc + 3] = v.w;
  }
  __syncthreads();
#pragma unroll
  for (int nn = 0; nn < 64; nn += 16) {
    const int n = tr + nn;
    ushort4 o;
    o.x = f2bf(tile[tc + 0][n]);
    o.y = f2bf(tile[tc + 1][n]);
    o.z = f2bf(tile[tc + 2][n]);
    o.w = f2bf(tile[tc + 3][n]);
    *(ushort4*)&Wt[(size_t)(n0 + n) * K + k0 + tc] = o;
  }
}

__global__ void cvt_bf16(const float* __restrict__ in,
                         unsigned short* __restrict__ out, int n4)
{
  const int i = blockIdx.x * blockDim.x + threadIdx.x;
  if (i >= n4) return;
  const float4 v = ((const float4*)in)[i];
  ushort4 o = { f2bf(v.x), f2bf(v.y), f2bf(v.z), f2bf(v.w) };
  ((ushort4*)out)[i] = o;
}

// ---------------------------------------------------------------------------
// V (bh,s,64) bf16 -> Vt (bh,64,s) bf16
// ---------------------------------------------------------------------------
__global__ __launch_bounds__(256) void trans_v(
    const unsigned short* __restrict__ v, unsigned short* __restrict__ vt)
{
  __shared__ unsigned short tile[64][66];
  const int st = blockIdx.x, bh = blockIdx.y;
  const int tid = threadIdx.x;
  const int r = tid >> 3, c = (tid & 7) << 3;
  const size_t base = (size_t)bh * (S_LEN * 64);
#pragma unroll
  for (int p = 0; p < 2; ++p) {
    const int s = r + p * 32;
    const uint4 raw = *(const uint4*)(v + base + (size_t)(st * 64 + s) * 64 + c);
    const unsigned short* pr = (const unsigned short*)&raw;
#pragma unroll
    for (int j = 0; j < 8; ++j) tile[s][c + j] = pr[j];
  }
  __syncthreads();
#pragma unroll
  for (int p = 0; p < 2; ++p) {
    const int hd = r + p * 32;
    ushort4 o[2];
#pragma unroll
    for (int j = 0; j < 8; ++j) ((unsigned short*)o)[j] = tile[c + j][hd];
    *(uint4*)(vt + (size_t)bh * (64 * S_LEN) + (size_t)hd * S_LEN + st * 64 + c) =
        *(const uint4*)o;
  }
}

// ---------------------------------------------------------------------------
// GEMM 128x128, BK=64, DOUBLE-buffered (for QKV N=3072 and FFN1 N=4096).
// 64 KB LDS -> 2 blocks/CU.  EPI 0: QKV scatter; EPI 2: bf16 gelu(acc+bias).
// ---------------------------------------------------------------------------
template <int EPI>
__global__ __launch_bounds__(256) void gemm128(
    const unsigned short* __restrict__ A,
    const unsigned short* __restrict__ Bt,
    const float* __restrict__ bias,
    const float* __restrict__ bias2,
    const float* __restrict__ bias3,
    int N, int K,
    unsigned short* __restrict__ bout)
{
  __shared__ __align__(16) unsigned short As[2][128 * 64];
  __shared__ __align__(16) unsigned short Bs[2][128 * 64];
  const int tn = blockIdx.x, tm = blockIdx.y;
  const int tid = threadIdx.x;
  const int wid = tid >> 6, lane = tid & 63;
  const int wm = wid >> 1, wn = wid & 1;
  const int l15 = lane & 15, lg = lane >> 4;
  const int srow = lane >> 3, sk8 = (lane & 7) << 3;

  f32x4 acc[4][4];
#pragma unroll
  for (int i = 0; i < 4; ++i)
#pragma unroll
    for (int j = 0; j < 4; ++j) acc[i][j] = (f32x4){0.f, 0.f, 0.f, 0.f};

  const size_t abase = (size_t)(tm * 128) * K;
  const size_t bbase = (size_t)(tn * 128) * K;

  auto STAGE = [&](int bufn, int kk) {
#pragma unroll
    for (int s = 0; s < 4; ++s) {
      const int row = wid * 32 + s * 8 + srow;
      const int sw = sk8 ^ swz(row);
      gload_lds16(A + abase + (size_t)row * K + kk + sw,
                  &As[bufn][(wid * 32 + s * 8) * 64]);
      gload_lds16(Bt + bbase + (size_t)row * K + kk + sw,
                  &Bs[bufn][(wid * 32 + s * 8) * 64]);
    }
  };

  STAGE(0, 0);
  __syncthreads();
  int cur = 0;
  for (int kk = 0; kk < K; kk += 64) {
    if (kk + 64 < K) STAGE(cur ^ 1, kk + 64);
#pragma unroll
    for (int sub = 0; sub < 2; ++sub) {
      bf16x8 af[4], bfr[4];
#pragma unroll
      for (int mr = 0; mr < 4; ++mr) {
        const int row = wm * 64 + mr * 16 + l15;
        af[mr] = *(const bf16x8*)&As[cur][row * 64 + ((sub * 32 + lg * 8) ^ swz(row))];
      }
#pragma unroll
      for (int nr = 0; nr < 4; ++nr) {
        const int row = wn * 64 + nr * 16 + l15;
        bfr[nr] = *(const bf16x8*)&Bs[cur][row * 64 + ((sub * 32 + lg * 8) ^ swz(row))];
      }
#pragma unroll
      for (int mr = 0; mr < 4; ++mr)
#pragma unroll
        for (int nr = 0; nr < 4; ++nr)
          acc[mr][nr] = mfma16(af[mr], bfr[nr], acc[mr][nr]);
    }
    __syncthreads();
    cur ^= 1;
  }

#pragma unroll
  for (int nr = 0; nr < 4; ++nr) {
    const int col = tn * 128 + wn * 64 + nr * 16 + l15;
    float bv;
    int which = 0, c = col;
    if (EPI == 0) {
      which = col >> 10;
      c = col & 1023;
      const float* bp = (which == 0) ? bias : (which == 1) ? bias2 : bias3;
      bv = bp[c];
    } else {
      bv = bias[col];
    }
#pragma unroll
    for (int mr = 0; mr < 4; ++mr) {
#pragma unroll
      for (int j = 0; j < 4; ++j) {
        const int row = tm * 128 + wm * 64 + mr * 16 + lg * 4 + j;
        float v = acc[mr][nr][j] + bv;
        if (EPI == 0) {
          if (which == 0) v *= 0.125f;           // 1/sqrt(hd)
          const int b = row >> 11, s = row & 2047, h = c >> 6, hd = c & 63;
          bout[(size_t)which * 4194304 +
               (((size_t)(b * NH + h)) * S_LEN + s) * 64 + hd] = f2bf(v);
        } else {
          const float gl = 0.5f * v * (1.f + erff(v * 0.70710678118654752f));
          bout[(size_t)row * N + col] = f2bf(gl);
        }
      }
    }
  }
}

// ---------------------------------------------------------------------------
// GEMM 64x128, BK=64, double-buffered (for N=1024 GEMMs: grid 512 = 2/CU).
// EPI 1: fp32 out = acc + bias + resf    (O-proj + residual x)
// EPI 3: fp32 out = acc + bias + bf2f(resb)  (FFN2 + residual sa)
// ---------------------------------------------------------------------------
template <int EPI>
__global__ __launch_bounds__(256) void gemmdb(
    const unsigned short* __restrict__ A,
    const unsigned short* __restrict__ Bt,
    const float* __restrict__ bias,
    int N, int K,
    float* __restrict__ fout,
    const float* __restrict__ resf,
    const unsigned short* __restrict__ resb)
{
  __shared__ __align__(16) unsigned short As[2][64 * 64];
  __shared__ __align__(16) unsigned short Bs[2][128 * 64];
  const int tn = blockIdx.x, tm = blockIdx.y;
  const int tid = threadIdx.x;
  const int wid = tid >> 6, lane = tid & 63;
  const int wm = wid >> 1, wn = wid & 1;
  const int l15 = lane & 15, lg = lane >> 4;
  const int srow = lane >> 3, sk8 = (lane & 7) << 3;

  f32x4 acc[2][4];
#pragma unroll
  for (int i = 0; i < 2; ++i)
#pragma unroll
    for (int j = 0; j < 4; ++j) acc[i][j] = (f32x4){0.f, 0.f, 0.f, 0.f};

  const size_t abase = (size_t)(tm * 64) * K;
  const size_t bbase = (size_t)(tn * 128) * K;

  auto STAGE = [&](int bufn, int kk) {
#pragma unroll
    for (int s = 0; s < 2; ++s) {
      const int row = wid * 16 + s * 8 + srow;
      gload_lds16(A + abase + (size_t)row * K + kk + (sk8 ^ swz(row)),
                  &As[bufn][(wid * 16 + s * 8) * 64]);
    }
#pragma unroll
    for (int s = 0; s < 4; ++s) {
      const int row = wid * 32 + s * 8 + srow;
      gload_lds16(Bt + bbase + (size_t)row * K + kk + (sk8 ^ swz(row)),
                  &Bs[bufn][(wid * 32 + s * 8) * 64]);
    }
  };

  STAGE(0, 0);
  __syncthreads();
  int cur = 0;
  for (int kk = 0; kk < K; kk += 64) {
    if (kk + 64 < K) STAGE(cur ^ 1, kk + 64);
#pragma unroll
    for (int sub = 0; sub < 2; ++sub) {
      bf16x8 af[2], bfr[4];
#pragma unroll
      for (int mr = 0; mr < 2; ++mr) {
        const int row = wm * 32 + mr * 16 + l15;
        af[mr] = *(const bf16x8*)&As[cur][row * 64 + ((sub * 32 + lg * 8) ^ swz(row))];
      }
#pragma unroll
      for (int nr = 0; nr < 4; ++nr) {
        const int row = wn * 64 + nr * 16 + l15;
        bfr[nr] = *(const bf16x8*)&Bs[cur][row * 64 + ((sub * 32 + lg * 8) ^ swz(row))];
      }
#pragma unroll
      for (int mr = 0; mr < 2; ++mr)
#pragma unroll
        for (int nr = 0; nr < 4; ++nr)
          acc[mr][nr] = mfma16(af[mr], bfr[nr], acc[mr][nr]);
    }
    __syncthreads();
    cur ^= 1;
  }

#pragma unroll
  for (int nr = 0; nr < 4; ++nr) {
    const int col = tn * 128 + wn * 64 + nr * 16 + l15;
    const float bv = bias[col];
#pragma unroll
    for (int mr = 0; mr < 2; ++mr) {
#pragma unroll
      for (int j = 0; j < 4; ++j) {
        const int row = tm * 64 + wm * 32 + mr * 16 + lg * 4 + j;
        const float v = acc[mr][nr][j] + bv;
        if (EPI == 1) {
          fout[(size_t)row * N + col] = v + resf[(size_t)row * N + col];
        } else {
          fout[(size_t)row * N + col] = v + bf2f(resb[(size_t)row * N + col]);
        }
      }
    }
  }
}

// ---------------------------------------------------------------------------
// Flash attention fwd, swapped-QK^T softmax (lane-local q-rows).
// 1D grid 512 blocks XCD-grouped; 512 threads = 8 waves x 16 q-rows.
// S^T = mfma(K,Q): lane holds q = lane&15, kv = nr*16 + (lane>>4)*4 + j.
// Row-max: lane tree + 2 shfl.  P packed as b64 writes.  Defer-max THR=8.
// q,k: (bh,s,64);  vt: (bh,64,s);  ctx out: (token,1024) bf16.
// ---------------------------------------------------------------------------
__global__ __launch_bounds__(512) void attn_fwd(
    const unsigned short* __restrict__ qg,
    const unsigned short* __restrict__ kg,
    const unsigned short* __restrict__ vtg,
    const int* __restrict__ amask,
    unsigned short* __restrict__ ctx)
{
  __shared__ __align__(16) unsigned short Ks[2][64 * 64];
  __shared__ __align__(16) unsigned short Vs[2][64 * 64];   // [hd][kv]
  __shared__ __align__(16) unsigned short Ps[8][16 * 72];
  __shared__ __align__(16) int mk[2][64];

  const int bx = blockIdx.x;
  const int qt = (bx >> 3) & 15;
  const int bh = ((bx & 7) << 2) | (bx >> 7);
  const int b = bh >> 4, h = bh & 15;
  const int tid = threadIdx.x;
  const int wid = tid >> 6, lane = tid & 63;
  const int l15 = lane & 15, lg = lane >> 4;
  const int srow = lane >> 3, sk8 = (lane & 7) << 3;

  // Q as B-fragment: lane holds col q=l15, k=hd=lg*8+i
  const size_t qoff =
      (((size_t)bh * S_LEN) + qt * 128 + wid * 16 + l15) * 64 + lg * 8;
  const bf16x8 aq0 = *(const bf16x8*)&qg[qoff];
  const bf16x8 aq1 = *(const bf16x8*)&qg[qoff + 32];

  f32x4 o_[4];
#pragma unroll
  for (int n = 0; n < 4; ++n) o_[n] = (f32x4){0.f, 0.f, 0.f, 0.f};
  float mreg = -3e38f, lsum = 0.f;

  const size_t kbase  = (size_t)bh * (S_LEN * 64);
  const size_t vtbase = (size_t)bh * (64 * S_LEN);
  unsigned short* Pw = &Ps[wid][0];
  const int rk = wid * 8 + srow;           // staging row (8 rows/wave)
  const int swr = sk8 ^ swz(rk);

  auto STAGE = [&](int bufn, int t) {
    gload_lds16(kg + kbase + (size_t)(t * 64 + rk) * 64 + swr,
                &Ks[bufn][wid * 8 * 64]);
    gload_lds16(vtg + vtbase + (size_t)rk * S_LEN + t * 64 + swr,
                &Vs[bufn][wid * 8 * 64]);
    if (tid < 64) mk[bufn][tid] = amask[b * S_LEN + t * 64 + tid];
  };

  STAGE(0, 0);
  __syncthreads();
  int cur = 0;

  for (int t = 0; t < S_LEN / 64; ++t) {
    if (t + 1 < S_LEN / 64) STAGE(cur ^ 1, t + 1);

    // S^T = K·Q^T : C[row kv_local = lg*4+j][col q = l15]
    __builtin_amdgcn_s_setprio(1);
    f32x4 sf[4];
#pragma unroll
    for (int nr = 0; nr < 4; ++nr) {
      const int kvloc = nr * 16 + l15;
      const int e = swz(kvloc);
      const bf16x8 bk0 = *(const bf16x8*)&Ks[cur][kvloc * 64 + ((lg * 8) ^ e)];
      const bf16x8 bk1 = *(const bf16x8*)&Ks[cur][kvloc * 64 + ((32 + lg * 8) ^ e)];
      f32x4 a = (f32x4){0.f, 0.f, 0.f, 0.f};
      a = mfma16(bk0, aq0, a);
      a = mfma16(bk1, aq1, a);
      sf[nr] = a;
    }
    __builtin_amdgcn_s_setprio(0);

    // mask (kv = nr*16 + lg*4 + j); int4 broadcast reads
#pragma unroll
    for (int nr = 0; nr < 4; ++nr) {
      const int4 mki = *(const int4*)&mk[cur][nr * 16 + lg * 4];
      if (mki.x == 0) sf[nr][0] = -3e38f;
      if (mki.y == 0) sf[nr][1] = -3e38f;
      if (mki.z == 0) sf[nr][2] = -3e38f;
      if (mki.w == 0) sf[nr][3] = -3e38f;
    }

    // row max: lane-local tree over 16 + 2 shfl (4 lanes share a row)
    float pmax = fmaxf(fmaxf(fmaxf(sf[0][0], sf[0][1]), fmaxf(sf[0][2], sf[0][3])),
                       fmaxf(fmaxf(sf[1][0], sf[1][1]), fmaxf(sf[1][2], sf[1][3])));
    pmax = fmaxf(pmax,
           fmaxf(fmaxf(fmaxf(sf[2][0], sf[2][1]), fmaxf(sf[2][2], sf[2][3])),
                 fmaxf(fmaxf(sf[3][0], sf[3][1]), fmaxf(sf[3][2], sf[3][3]))));
    pmax = fmaxf(pmax, __shfl_xor(pmax, 16));
    pmax = fmaxf(pmax, __shfl_xor(pmax, 32));

    // defer-max: rescale only when the running max grew by > 8
    if (__any(pmax > mreg + 8.f)) {
      const float mn = fmaxf(mreg, pmax);
      const float sc = __expf(mreg - mn);
      mreg = mn;
      lsum *= sc;
      float scr[4];
#pragma unroll
      for (int j = 0; j < 4; ++j) scr[j] = __shfl(sc, lg * 4 + j);
#pragma unroll
      for (int n = 0; n < 4; ++n) {
        o_[n][0] *= scr[0]; o_[n][1] *= scr[1];
        o_[n][2] *= scr[2]; o_[n][3] *= scr[3];
      }
    }

    // P = exp(S - m), packed bf16 b64 stores (consecutive kv)
    asm volatile("s_waitcnt lgkmcnt(0)" ::: "memory");
#pragma unroll
    for (int nr = 0; nr < 4; ++nr) {
      const float p0 = __expf(sf[nr][0] - mreg);
      const float p1 = __expf(sf[nr][1] - mreg);
      const float p2 = __expf(sf[nr][2] - mreg);
      const float p3 = __expf(sf[nr][3] - mreg);
      lsum += (p0 + p1) + (p2 + p3);
      bf16x4v pk;
      pk[0] = (__bf16)p0; pk[1] = (__bf16)p1;
      pk[2] = (__bf16)p2; pk[3] = (__bf16)p3;
      *(bf16x4v*)&Pw[l15 * 72 + nr * 16 + lg * 4] = pk;
    }
    asm volatile("s_waitcnt lgkmcnt(0)" ::: "memory");

    // PV: A = P rows q, B = V^T  ->  o_ rows q = lg*4+j, col hd
    __builtin_amdgcn_s_setprio(1);
    {
      const bf16x8 pa0 = *(const bf16x8*)&Pw[l15 * 72 + lg * 8];
      const bf16x8 pa1 = *(const bf16x8*)&Pw[l15 * 72 + 32 + lg * 8];
#pragma unroll
      for (int n = 0; n < 4; ++n) {
        const int hd = n * 16 + l15;
        const int eh = swz(hd);
        const bf16x8 bv0 = *(const bf16x8*)&Vs[cur][hd * 64 + ((lg * 8) ^ eh)];
        const bf16x8 bv1 = *(const bf16x8*)&Vs[cur][hd * 64 + ((32 + lg * 8) ^ eh)];
        o_[n] = mfma16(pa0, bv0, o_[n]);
        o_[n] = mfma16(pa1, bv1, o_[n]);
      }
    }
    __builtin_amdgcn_s_setprio(0);
    __syncthreads();
    cur ^= 1;
  }

  // final: row-sum lives per lane (row q=l15); reduce over the 4 lg lanes
  lsum += __shfl_xor(lsum, 16);
  lsum += __shfl_xor(lsum, 32);
  const float rinv = 1.f / lsum;
  float rj[4];
#pragma unroll
  for (int j = 0; j < 4; ++j) rj[j] = __shfl(rinv, lg * 4 + j);
#pragma unroll
  for (int n = 0; n < 4; ++n) {
#pragma unroll
    for (int j = 0; j < 4; ++j) {
      const int sr = qt * 128 + wid * 16 + lg * 4 + j;
      const size_t idx = ((size_t)b * S_LEN + sr) * DIM_ + h * 64 + n * 16 + l15;
      ctx[idx] = f2bf(o_[n][j] * rj[j]);
    }
  }
}

// ---------------------------------------------------------------------------
// LayerNorm rows of 1024 fp32.  OUTBF=1 -> bf16 out, else fp32 (in-place ok).
// ---------------------------------------------------------------------------
template <int OUTBF>
__global__ __launch_bounds__(256) void ln_fused(
    const float* __restrict__ in, const float* __restrict__ g,
    const float* __restrict__ be,
    float* __restrict__ fout, unsigned short* __restrict__ bout)
{
  const int row = blockIdx.x, tid = threadIdx.x;
  const float4 v = ((const float4*)(in + (size_t)row * DIM_))[tid];
  float s = v.x + v.y + v.z + v.w;
  float s2 = v.x * v.x + v.y * v.y + v.z * v.z + v.w * v.w;
#pragma unroll
  for (int off = 1; off < 64; off <<= 1) {
    s += __shfl_xor(s, off);
    s2 += __shfl_xor(s2, off);
  }
  __shared__ float rs[4], rs2[4];
  if ((tid & 63) == 0) { rs[tid >> 6] = s; rs2[tid >> 6] = s2; }
  __syncthreads();
  s  = rs[0] + rs[1] + rs[2] + rs[3];
  s2 = rs2[0] + rs2[1] + rs2[2] + rs2[3];
  const float mean = s * (1.f / DIM_);
  const float var = fmaxf(s2 * (1.f / DIM_) - mean * mean, 0.f);
  const float inv = rsqrtf(var + 1e-12f);
  const float4 gv = ((const float4*)g)[tid];
  const float4 bv = ((const float4*)be)[tid];
  const float o0 = (v.x - mean) * inv * gv.x + bv.x;
  const float o1 = (v.y - mean) * inv * gv.y + bv.y;
  const float o2 = (v.z - mean) * inv * gv.z + bv.z;
  const float o3 = (v.w - mean) * inv * gv.w + bv.w;
  if (OUTBF) {
    ushort4 o = { f2bf(o0), f2bf(o1), f2bf(o2), f2bf(o3) };
    ((ushort4*)(bout + (size_t)row * DIM_))[tid] = o;
  } else {
    ((float4*)(fout + (size_t)row * DIM_))[tid] = make_float4(o0, o1, o2, o3);
  }
}

// ---------------------------------------------------------------------------
extern "C" void kernel_launch(void* const* d_in, const int* in_sizes, int n_in,
                              void* d_out, int out_size, void* d_ws, size_t ws_size,
                              hipStream_t stream)
{
  const float* x   = (const float*)d_in[0];
  const int* amask = (const int*)d_in[1];
  const float* Wq  = (const float*)d_in[2];
  const float* bq  = (const float*)d_in[3];
  const float* Wk  = (const float*)d_in[4];
  const float* bk  = (const float*)d_in[5];
  const float* Wv  = (const float*)d_in[6];
  const float* bv  = (const float*)d_in[7];
  const float* Wo  = (const float*)d_in[8];
  const float* bo  = (const float*)d_in[9];
  const float* g1  = (const float*)d_in[10];
  const float* be1 = (const float*)d_in[11];
  const float* W1  = (const float*)d_in[12];
  const float* b1  = (const float*)d_in[13];
  const float* W2  = (const float*)d_in[14];
  const float* b2  = (const float*)d_in[15];
  const float* g2  = (const float*)d_in[16];
  const float* be2 = (const float*)d_in[17];
  float* out = (float*)d_out;

  char* ws = (char*)d_ws;
  const size_t MB = (size_t)1 << 20;
  unsigned short* wqkvT = (unsigned short*)(ws + 0 * MB);   // [3072][1024]
  unsigned short* wqt = wqkvT;
  unsigned short* wkt = (unsigned short*)(ws + 2 * MB);
  unsigned short* wvt = (unsigned short*)(ws + 4 * MB);
  unsigned short* wot = (unsigned short*)(ws + 6 * MB);
  unsigned short* w1t = (unsigned short*)(ws + 8 * MB);
  unsigned short* w2t = (unsigned short*)(ws + 16 * MB);
  unsigned short* qb  = (unsigned short*)(ws + 24 * MB);    // q,k,v contiguous
  unsigned short* xb  = (unsigned short*)(ws + 48 * MB);
  unsigned short* vtb = (unsigned short*)(ws + 48 * MB);    // vt (after xb dead)
  unsigned short* ctx = (unsigned short*)(ws + 56 * MB);
  unsigned short* sab = qb;                                  // reuse after attn
  unsigned short* hb  = (unsigned short*)(ws + 32 * MB);     // reuse [32,64)
  float* preln = out;                                        // d_out as scratch

  trans_cvt4<<<dim3(16, 16, 4), 256, 0, stream>>>(Wq, Wk, Wv, Wo,
                                                  wqt, wkt, wvt, wot);
  trans_cvt<<<dim3(64, 16), 256, 0, stream>>>(W1, w1t, 1024, 4096);
  trans_cvt<<<dim3(16, 64), 256, 0, stream>>>(W2, w2t, 4096, 1024);
  cvt_bf16<<<4096, 256, 0, stream>>>(x, xb, 4096 * 1024 / 4);

  // fused QKV projection (N=3072), scatter to (bh,s,hd)  [128^2 dbuf]
  gemm128<0><<<dim3(24, 32), 256, 0, stream>>>(xb, wqkvT, bq, bk, bv,
      3072, 1024, qb);

  // V -> Vt (bh,64,s); xb is dead now
  trans_v<<<dim3(32, 32), 256, 0, stream>>>(qb + 2 * 4194304, vtb);

  // attention (XCD-grouped 1D grid)
  attn_fwd<<<512, 512, 0, stream>>>(qb, qb + 4194304, vtb, amask, ctx);

  // O-proj + bias + residual(x) -> preln (d_out)
  gemmdb<1><<<dim3(8, 64), 256, 0, stream>>>(ctx, wot, bo, 1024, 1024,
      preln, x, nullptr);
  ln_fused<1><<<4096, 256, 0, stream>>>(preln, g1, be1, nullptr, sab);

  // FFN  [FFN1 on 128^2 dbuf; FFN2 on 64x128 dbuf]
  gemm128<2><<<dim3(32, 32), 256, 0, stream>>>(sab, w1t, b1, nullptr, nullptr,
      4096, 1024, hb);
  gemmdb<3><<<dim3(8, 64), 256, 0, stream>>>(hb, w2t, b2, 1024, 4096,
      preln, nullptr, sab);
  ln_fused<0><<<4096, 256, 0, stream>>>(preln, g2, be2, out, nullptr);
}